// Round 1
// baseline (1410.804 us; speedup 1.0000x reference)
//
#include <hip/hip_runtime.h>
#include <hip/hip_bf16.h>

// Problem constants
#define B_SZ 8
#define SEQ 512
#define D 768
#define D3 2304
#define NH 12
#define HD 64
#define NE 8
#define RANK 16
#define TOPK 2
#define TT (B_SZ * SEQ)           // 4096 tokens
#define SCALING 2.0f              // ALPHA / RANK = 32/16

// ---------------------------------------------------------------------------
// Kernel 1: router (softmax gate, top-2) + LoRA down-projection for the two
// selected experts, with weight*scaling folded into the rank-16 vectors.
// One wave (64 threads) per token.
// ---------------------------------------------------------------------------
__global__ __launch_bounds__(64) void k_router(
    const float* __restrict__ x, const float* __restrict__ Wg,
    const float* __restrict__ bg, const float* __restrict__ A,
    float* __restrict__ vlora, int* __restrict__ idx2)
{
    const int t = blockIdx.x;
    const int l = threadIdx.x;
    const float* xr = x + (size_t)t * D;

    // cache this token's row: 12 floats per lane (stride 64)
    float xv[12];
#pragma unroll
    for (int i = 0; i < 12; ++i) xv[i] = xr[l + 64 * i];

    // 8 gate logits via wave reductions
    float p[NE];
#pragma unroll
    for (int e = 0; e < NE; ++e) {
        const float* w = Wg + (size_t)e * D;
        float s = 0.f;
#pragma unroll
        for (int i = 0; i < 12; ++i) s += xv[i] * w[l + 64 * i];
#pragma unroll
        for (int off = 32; off; off >>= 1) s += __shfl_xor(s, off);
        p[e] = s + bg[e];
    }
    // softmax (all lanes redundantly)
    float mx = p[0];
#pragma unroll
    for (int e = 1; e < NE; ++e) mx = fmaxf(mx, p[e]);
    float den = 0.f;
#pragma unroll
    for (int e = 0; e < NE; ++e) { p[e] = expf(p[e] - mx); den += p[e]; }
    // top-2 (strict > keeps lowest index on ties, matching lax.top_k)
    int i0 = 0;
#pragma unroll
    for (int e = 1; e < NE; ++e) if (p[e] > p[i0]) i0 = e;
    int i1 = (i0 == 0) ? 1 : 0;
#pragma unroll
    for (int e = 0; e < NE; ++e) if (e != i1 && e != i0 && p[e] > p[i1]) i1 = e;
    const float w0 = p[i0] / den * SCALING;
    const float w1 = p[i1] / den * SCALING;
    if (l == 0) { idx2[2 * t] = i0; idx2[2 * t + 1] = i1; }

    // LoRA down for the two experts; fold weight*scaling in
#pragma unroll
    for (int j = 0; j < 2; ++j) {
        const int e = j ? i1 : i0;
        const float wj = j ? w1 : w0;
        const float* Ae = A + (size_t)e * RANK * D;
#pragma unroll
        for (int r = 0; r < RANK; ++r) {
            const float* a = Ae + (size_t)r * D;
            float s = 0.f;
#pragma unroll
            for (int i = 0; i < 12; ++i) s += xv[i] * a[l + 64 * i];
#pragma unroll
            for (int off = 32; off; off >>= 1) s += __shfl_xor(s, off);
            if (l == 0) vlora[t * 32 + j * 16 + r] = s * wj;
        }
    }
}

// ---------------------------------------------------------------------------
// Kernel 2: tiled fp32 GEMM  C[m][n] = sum_k A[m][k]*B[n][k] + bias[n]
// (both operands row-major with contiguous K: "NT" layout).
// Optional fused LoRA-up epilogue (adds sum_j B_up[e_j][n][:] . v_j[m][:]).
// 128x128 tile, BK=16, 256 threads, 8x8 accumulators per thread.
// ---------------------------------------------------------------------------
#define BM 128
#define BN 128
#define BK 16

__device__ __forceinline__ float dot4(float4 a, float4 b) {
    return a.x * b.x + a.y * b.y + a.z * b.z + a.w * b.w;
}

template <bool LORA>
__global__ __launch_bounds__(256, 2) void k_gemm_nt(
    const float* __restrict__ Amat, const float* __restrict__ Bmat,
    const float* __restrict__ bias, float* __restrict__ C,
    int M, int N, int K,
    const float* __restrict__ vl, const int* __restrict__ idx2,
    const float* __restrict__ Bup)
{
    __shared__ float As[BK][BM + 4];
    __shared__ float Bs[BK][BN + 4];

    const int tid = threadIdx.x;
    const int tn = tid & 15;        // 0..15 -> 8 cols each
    const int tm = tid >> 4;        // 0..15 -> 8 rows each
    const int m0 = blockIdx.y * BM;
    const int n0 = blockIdx.x * BN;

    float acc[8][8] = {};

    const int lrow = tid >> 1;            // 0..127
    const int lcol = (tid & 1) * 8;       // 0 or 8
    const float* Aptr = Amat + (size_t)(m0 + lrow) * K + lcol;
    const float* Bptr = Bmat + (size_t)(n0 + lrow) * K + lcol;

    for (int k0 = 0; k0 < K; k0 += BK) {
        float4 a0 = *(const float4*)(Aptr + k0);
        float4 a1 = *(const float4*)(Aptr + k0 + 4);
        float4 b0 = *(const float4*)(Bptr + k0);
        float4 b1 = *(const float4*)(Bptr + k0 + 4);
        __syncthreads();   // previous iteration's reads done
        As[lcol + 0][lrow] = a0.x; As[lcol + 1][lrow] = a0.y;
        As[lcol + 2][lrow] = a0.z; As[lcol + 3][lrow] = a0.w;
        As[lcol + 4][lrow] = a1.x; As[lcol + 5][lrow] = a1.y;
        As[lcol + 6][lrow] = a1.z; As[lcol + 7][lrow] = a1.w;
        Bs[lcol + 0][lrow] = b0.x; Bs[lcol + 1][lrow] = b0.y;
        Bs[lcol + 2][lrow] = b0.z; Bs[lcol + 3][lrow] = b0.w;
        Bs[lcol + 4][lrow] = b1.x; Bs[lcol + 5][lrow] = b1.y;
        Bs[lcol + 6][lrow] = b1.z; Bs[lcol + 7][lrow] = b1.w;
        __syncthreads();
#pragma unroll
        for (int kk = 0; kk < BK; ++kk) {
            float4 xa0 = *(const float4*)&As[kk][tm * 8];
            float4 xa1 = *(const float4*)&As[kk][tm * 8 + 4];
            float4 xb0 = *(const float4*)&Bs[kk][tn * 8];
            float4 xb1 = *(const float4*)&Bs[kk][tn * 8 + 4];
            float av[8] = {xa0.x, xa0.y, xa0.z, xa0.w, xa1.x, xa1.y, xa1.z, xa1.w};
            float bv[8] = {xb0.x, xb0.y, xb0.z, xb0.w, xb1.x, xb1.y, xb1.z, xb1.w};
#pragma unroll
            for (int i = 0; i < 8; ++i)
#pragma unroll
                for (int j = 0; j < 8; ++j)
                    acc[i][j] += av[i] * bv[j];
        }
    }

    // epilogue
#pragma unroll
    for (int i = 0; i < 8; ++i) {
        const int m = m0 + tm * 8 + i;
        float4 vv[8];
        int e0 = 0, e1 = 0;
        if (LORA) {
            e0 = idx2[2 * m]; e1 = idx2[2 * m + 1];
            const float4* vp = (const float4*)(vl + (size_t)m * 32);
#pragma unroll
            for (int q = 0; q < 8; ++q) vv[q] = vp[q];
        }
        float out[8];
#pragma unroll
        for (int j = 0; j < 8; ++j) {
            const int n = n0 + tn * 8 + j;
            float c = acc[i][j] + bias[n];
            if (LORA) {
                const float4* u0 = (const float4*)(Bup + ((size_t)e0 * D3 + n) * RANK);
                const float4* u1 = (const float4*)(Bup + ((size_t)e1 * D3 + n) * RANK);
                float s = 0.f;
#pragma unroll
                for (int q = 0; q < 4; ++q) s += dot4(vv[q], u0[q]);
#pragma unroll
                for (int q = 0; q < 4; ++q) s += dot4(vv[4 + q], u1[q]);
                c += s;
            }
            out[j] = c;
        }
        float* cp = C + (size_t)m * N + n0 + tn * 8;
        *(float4*)(cp)     = make_float4(out[0], out[1], out[2], out[3]);
        *(float4*)(cp + 4) = make_float4(out[4], out[5], out[6], out[7]);
    }
}

// ---------------------------------------------------------------------------
// Kernel 3: flash-style attention, fp32. One thread per query row.
// Blocks of 64 threads (one wave) -> 64 q rows of one (b,h).
// qkv layout: [t][part*768 + h*64 + d], part 0=q 1=k 2=v.
// Output written as [B,S,D] (d = h*64 + hd) ready for the projection GEMM.
// ---------------------------------------------------------------------------
__global__ __launch_bounds__(64) void k_attn(
    const float* __restrict__ qkv, float* __restrict__ out)
{
    const int bid = blockIdx.x;
    const int qb = bid & 7;               // q block (64 rows)
    const int h = (bid >> 3) % NH;
    const int b = bid / (8 * NH);
    const int row = qb * 64 + threadIdx.x;

    const float* base = qkv + (size_t)(b * SEQ) * D3 + h * HD;
    const float4* qp = (const float4*)(base + (size_t)row * D3);

    float4 q4[16], o4[16];
#pragma unroll
    for (int dc = 0; dc < 16; ++dc) {
        float4 qv = qp[dc];
        q4[dc] = make_float4(qv.x * 0.125f, qv.y * 0.125f, qv.z * 0.125f, qv.w * 0.125f);
        o4[dc] = make_float4(0.f, 0.f, 0.f, 0.f);
    }
    float m = -INFINITY, l = 0.f;

    for (int j0 = 0; j0 < SEQ; j0 += 16) {
        float s[16];
#pragma unroll
        for (int jj = 0; jj < 16; ++jj) {
            const float4* kp = (const float4*)(base + (size_t)(j0 + jj) * D3 + D);
            float acc = 0.f;
#pragma unroll
            for (int dc = 0; dc < 16; ++dc) {
                float4 kv = kp[dc];
                acc += q4[dc].x * kv.x + q4[dc].y * kv.y + q4[dc].z * kv.z + q4[dc].w * kv.w;
            }
            s[jj] = acc;
        }
        float mx = m;
#pragma unroll
        for (int jj = 0; jj < 16; ++jj) mx = fmaxf(mx, s[jj]);
        const float corr = expf(m - mx);
        m = mx;
        float sum = 0.f;
#pragma unroll
        for (int jj = 0; jj < 16; ++jj) { s[jj] = expf(s[jj] - m); sum += s[jj]; }
        l = l * corr + sum;
#pragma unroll
        for (int dc = 0; dc < 16; ++dc) {
            o4[dc].x *= corr; o4[dc].y *= corr; o4[dc].z *= corr; o4[dc].w *= corr;
        }
#pragma unroll
        for (int jj = 0; jj < 16; ++jj) {
            const float sj = s[jj];
            const float4* vp = (const float4*)(base + (size_t)(j0 + jj) * D3 + 2 * D);
#pragma unroll
            for (int dc = 0; dc < 16; ++dc) {
                float4 vv = vp[dc];
                o4[dc].x += sj * vv.x; o4[dc].y += sj * vv.y;
                o4[dc].z += sj * vv.z; o4[dc].w += sj * vv.w;
            }
        }
    }
    const float inv = 1.f / l;
    float4* op = (float4*)(out + (size_t)(b * SEQ + row) * D + h * HD);
#pragma unroll
    for (int dc = 0; dc < 16; ++dc) {
        op[dc] = make_float4(o4[dc].x * inv, o4[dc].y * inv, o4[dc].z * inv, o4[dc].w * inv);
    }
}

// ---------------------------------------------------------------------------
extern "C" void kernel_launch(void* const* d_in, const int* in_sizes, int n_in,
                              void* d_out, int out_size, void* d_ws, size_t ws_size,
                              hipStream_t stream)
{
    const float* x      = (const float*)d_in[0];
    const float* W_qkv  = (const float*)d_in[1];
    const float* b_qkv  = (const float*)d_in[2];
    const float* W_gate = (const float*)d_in[3];
    const float* b_gate = (const float*)d_in[4];
    const float* A      = (const float*)d_in[5];
    const float* B_lora = (const float*)d_in[6];
    const float* W_proj = (const float*)d_in[7];
    const float* b_proj = (const float*)d_in[8];
    float* out = (float*)d_out;

    // workspace layout (floats)
    float* qkv  = (float*)d_ws;                        // T * 3D
    float* attn = qkv + (size_t)TT * D3;               // T * D
    float* vl   = attn + (size_t)TT * D;               // T * 32
    int*   idx2 = (int*)(vl + (size_t)TT * 32);        // T * 2

    // 1. router + LoRA down
    k_router<<<TT, 64, 0, stream>>>(x, W_gate, b_gate, A, vl, idx2);

    // 2. QKV GEMM + bias + fused LoRA up
    {
        dim3 grid(D3 / BN, TT / BM);
        k_gemm_nt<true><<<grid, 256, 0, stream>>>(x, W_qkv, b_qkv, qkv,
                                                  TT, D3, D, vl, idx2, B_lora);
    }

    // 3. attention
    k_attn<<<B_SZ * NH * 8, 64, 0, stream>>>(qkv, attn);

    // 4. output projection
    {
        dim3 grid(D / BN, TT / BM);
        k_gemm_nt<false><<<grid, 256, 0, stream>>>(attn, W_proj, b_proj, out,
                                                   TT, D, D, nullptr, nullptr, nullptr);
    }
}

// Round 2
// 854.733 us; speedup vs baseline: 1.6506x; 1.6506x over previous
//
#include <hip/hip_runtime.h>
#include <hip/hip_bf16.h>

// Problem constants
#define B_SZ 8
#define SEQ 512
#define D 768
#define D3 2304
#define NH 12
#define HD 64
#define NE 8
#define RANK 16
#define TOPK 2
#define TT (B_SZ * SEQ)           // 4096 tokens
#define SCALING 2.0f              // ALPHA / RANK = 32/16
#define NCH 4                     // KV chunks for split attention
#define KVC (SEQ / NCH)           // 128 KV rows per chunk
#define RGT (B_SZ * NH * SEQ)     // 49152 global attention rows

// ---------------------------------------------------------------------------
// Kernel 1: router (softmax gate, top-2) + LoRA down-projection for the two
// selected experts, with weight*scaling folded into the rank-16 vectors.
// One wave (64 threads) per token.
// ---------------------------------------------------------------------------
__global__ __launch_bounds__(64) void k_router(
    const float* __restrict__ x, const float* __restrict__ Wg,
    const float* __restrict__ bg, const float* __restrict__ A,
    float* __restrict__ vlora, int* __restrict__ idx2)
{
    const int t = blockIdx.x;
    const int l = threadIdx.x;
    const float* xr = x + (size_t)t * D;

    float xv[12];
#pragma unroll
    for (int i = 0; i < 12; ++i) xv[i] = xr[l + 64 * i];

    float p[NE];
#pragma unroll
    for (int e = 0; e < NE; ++e) {
        const float* w = Wg + (size_t)e * D;
        float s = 0.f;
#pragma unroll
        for (int i = 0; i < 12; ++i) s += xv[i] * w[l + 64 * i];
#pragma unroll
        for (int off = 32; off; off >>= 1) s += __shfl_xor(s, off);
        p[e] = s + bg[e];
    }
    float mx = p[0];
#pragma unroll
    for (int e = 1; e < NE; ++e) mx = fmaxf(mx, p[e]);
    float den = 0.f;
#pragma unroll
    for (int e = 0; e < NE; ++e) { p[e] = expf(p[e] - mx); den += p[e]; }
    int i0 = 0;
#pragma unroll
    for (int e = 1; e < NE; ++e) if (p[e] > p[i0]) i0 = e;
    int i1 = (i0 == 0) ? 1 : 0;
#pragma unroll
    for (int e = 0; e < NE; ++e) if (e != i1 && e != i0 && p[e] > p[i1]) i1 = e;
    const float w0 = p[i0] / den * SCALING;
    const float w1 = p[i1] / den * SCALING;
    if (l == 0) { idx2[2 * t] = i0; idx2[2 * t + 1] = i1; }

#pragma unroll
    for (int j = 0; j < 2; ++j) {
        const int e = j ? i1 : i0;
        const float wj = j ? w1 : w0;
        const float* Ae = A + (size_t)e * RANK * D;
#pragma unroll
        for (int r = 0; r < RANK; ++r) {
            const float* a = Ae + (size_t)r * D;
            float s = 0.f;
#pragma unroll
            for (int i = 0; i < 12; ++i) s += xv[i] * a[l + 64 * i];
#pragma unroll
            for (int off = 32; off; off >>= 1) s += __shfl_xor(s, off);
            if (l == 0) vlora[t * 32 + j * 16 + r] = s * wj;
        }
    }
}

// ---------------------------------------------------------------------------
// Kernel 2: tiled fp32 GEMM  C[m][n] = sum_k A[m][k]*B[n][k] + bias[n]
// Optional fused LoRA-up epilogue.
// ---------------------------------------------------------------------------
#define BM 128
#define BN 128
#define BK 16

__device__ __forceinline__ float dot4(float4 a, float4 b) {
    return a.x * b.x + a.y * b.y + a.z * b.z + a.w * b.w;
}

template <bool LORA>
__global__ __launch_bounds__(256, 2) void k_gemm_nt(
    const float* __restrict__ Amat, const float* __restrict__ Bmat,
    const float* __restrict__ bias, float* __restrict__ C,
    int M, int N, int K,
    const float* __restrict__ vl, const int* __restrict__ idx2,
    const float* __restrict__ Bup)
{
    __shared__ float As[BK][BM + 4];
    __shared__ float Bs[BK][BN + 4];

    const int tid = threadIdx.x;
    const int tn = tid & 15;
    const int tm = tid >> 4;
    const int m0 = blockIdx.y * BM;
    const int n0 = blockIdx.x * BN;

    float acc[8][8] = {};

    const int lrow = tid >> 1;
    const int lcol = (tid & 1) * 8;
    const float* Aptr = Amat + (size_t)(m0 + lrow) * K + lcol;
    const float* Bptr = Bmat + (size_t)(n0 + lrow) * K + lcol;

    for (int k0 = 0; k0 < K; k0 += BK) {
        float4 a0 = *(const float4*)(Aptr + k0);
        float4 a1 = *(const float4*)(Aptr + k0 + 4);
        float4 b0 = *(const float4*)(Bptr + k0);
        float4 b1 = *(const float4*)(Bptr + k0 + 4);
        __syncthreads();
        As[lcol + 0][lrow] = a0.x; As[lcol + 1][lrow] = a0.y;
        As[lcol + 2][lrow] = a0.z; As[lcol + 3][lrow] = a0.w;
        As[lcol + 4][lrow] = a1.x; As[lcol + 5][lrow] = a1.y;
        As[lcol + 6][lrow] = a1.z; As[lcol + 7][lrow] = a1.w;
        Bs[lcol + 0][lrow] = b0.x; Bs[lcol + 1][lrow] = b0.y;
        Bs[lcol + 2][lrow] = b0.z; Bs[lcol + 3][lrow] = b0.w;
        Bs[lcol + 4][lrow] = b1.x; Bs[lcol + 5][lrow] = b1.y;
        Bs[lcol + 6][lrow] = b1.z; Bs[lcol + 7][lrow] = b1.w;
        __syncthreads();
#pragma unroll
        for (int kk = 0; kk < BK; ++kk) {
            float4 xa0 = *(const float4*)&As[kk][tm * 8];
            float4 xa1 = *(const float4*)&As[kk][tm * 8 + 4];
            float4 xb0 = *(const float4*)&Bs[kk][tn * 8];
            float4 xb1 = *(const float4*)&Bs[kk][tn * 8 + 4];
            float av[8] = {xa0.x, xa0.y, xa0.z, xa0.w, xa1.x, xa1.y, xa1.z, xa1.w};
            float bv[8] = {xb0.x, xb0.y, xb0.z, xb0.w, xb1.x, xb1.y, xb1.z, xb1.w};
#pragma unroll
            for (int i = 0; i < 8; ++i)
#pragma unroll
                for (int j = 0; j < 8; ++j)
                    acc[i][j] += av[i] * bv[j];
        }
    }

#pragma unroll
    for (int i = 0; i < 8; ++i) {
        const int m = m0 + tm * 8 + i;
        float4 vv[8];
        int e0 = 0, e1 = 0;
        if (LORA) {
            e0 = idx2[2 * m]; e1 = idx2[2 * m + 1];
            const float4* vp = (const float4*)(vl + (size_t)m * 32);
#pragma unroll
            for (int q = 0; q < 8; ++q) vv[q] = vp[q];
        }
        float out[8];
#pragma unroll
        for (int j = 0; j < 8; ++j) {
            const int n = n0 + tn * 8 + j;
            float c = acc[i][j] + bias[n];
            if (LORA) {
                const float4* u0 = (const float4*)(Bup + ((size_t)e0 * D3 + n) * RANK);
                const float4* u1 = (const float4*)(Bup + ((size_t)e1 * D3 + n) * RANK);
                float s = 0.f;
#pragma unroll
                for (int q = 0; q < 4; ++q) s += dot4(vv[q], u0[q]);
#pragma unroll
                for (int q = 0; q < 4; ++q) s += dot4(vv[4 + q], u1[q]);
                c += s;
            }
            out[j] = c;
        }
        float* cp = C + (size_t)m * N + n0 + tn * 8;
        *(float4*)(cp)     = make_float4(out[0], out[1], out[2], out[3]);
        *(float4*)(cp + 4) = make_float4(out[4], out[5], out[6], out[7]);
    }
}

// ---------------------------------------------------------------------------
// Kernel 3a: split-KV flash attention. One wave per (b, h, q-block64, chunk).
// Stores unnormalized o plus (m, l) partials.
// ---------------------------------------------------------------------------
__global__ __launch_bounds__(64) void k_attn_split(
    const float* __restrict__ qkv, float* __restrict__ po,
    float* __restrict__ pm, float* __restrict__ pl)
{
    const int bid = blockIdx.x;
    const int c = bid & (NCH - 1);
    const int qb = (bid >> 2) & 7;
    const int h = (bid >> 5) % NH;
    const int b = bid / (32 * NH);
    const int row = qb * 64 + threadIdx.x;
    const int rg = (b * NH + h) * SEQ + row;

    const float* base = qkv + (size_t)(b * SEQ) * D3 + h * HD;
    const float4* qp = (const float4*)(base + (size_t)row * D3);

    float4 q4[16], o4[16];
#pragma unroll
    for (int dc = 0; dc < 16; ++dc) {
        float4 qv = qp[dc];
        q4[dc] = make_float4(qv.x * 0.125f, qv.y * 0.125f, qv.z * 0.125f, qv.w * 0.125f);
        o4[dc] = make_float4(0.f, 0.f, 0.f, 0.f);
    }
    float m = -INFINITY, l = 0.f;

    const int j_lo = c * KVC, j_hi = j_lo + KVC;
    for (int j0 = j_lo; j0 < j_hi; j0 += 16) {
        float s[16];
#pragma unroll
        for (int jj = 0; jj < 16; ++jj) {
            const float4* kp = (const float4*)(base + (size_t)(j0 + jj) * D3 + D);
            float acc = 0.f;
#pragma unroll
            for (int dc = 0; dc < 16; ++dc) {
                float4 kv = kp[dc];
                acc += q4[dc].x * kv.x + q4[dc].y * kv.y + q4[dc].z * kv.z + q4[dc].w * kv.w;
            }
            s[jj] = acc;
        }
        float mx = m;
#pragma unroll
        for (int jj = 0; jj < 16; ++jj) mx = fmaxf(mx, s[jj]);
        const float corr = expf(m - mx);
        m = mx;
        float sum = 0.f;
#pragma unroll
        for (int jj = 0; jj < 16; ++jj) { s[jj] = expf(s[jj] - m); sum += s[jj]; }
        l = l * corr + sum;
#pragma unroll
        for (int dc = 0; dc < 16; ++dc) {
            o4[dc].x *= corr; o4[dc].y *= corr; o4[dc].z *= corr; o4[dc].w *= corr;
        }
#pragma unroll
        for (int jj = 0; jj < 16; ++jj) {
            const float sj = s[jj];
            const float4* vp = (const float4*)(base + (size_t)(j0 + jj) * D3 + 2 * D);
#pragma unroll
            for (int dc = 0; dc < 16; ++dc) {
                float4 vv = vp[dc];
                o4[dc].x += sj * vv.x; o4[dc].y += sj * vv.y;
                o4[dc].z += sj * vv.z; o4[dc].w += sj * vv.w;
            }
        }
    }
    float4* op = (float4*)(po + ((size_t)c * RGT + rg) * HD);
#pragma unroll
    for (int dc = 0; dc < 16; ++dc) op[dc] = o4[dc];
    pm[(size_t)c * RGT + rg] = m;
    pl[(size_t)c * RGT + rg] = l;
}

// ---------------------------------------------------------------------------
// Kernel 3b: combine partials. One thread per (row, float4-column).
// ---------------------------------------------------------------------------
__global__ __launch_bounds__(256) void k_attn_combine(
    const float* __restrict__ po, const float* __restrict__ pm,
    const float* __restrict__ pl, float* __restrict__ attn)
{
    const int gid = blockIdx.x * 256 + threadIdx.x;
    const int rg = gid >> 4;
    const int d4 = gid & 15;

    float mc[NCH], lc[NCH];
#pragma unroll
    for (int c = 0; c < NCH; ++c) {
        mc[c] = pm[(size_t)c * RGT + rg];
        lc[c] = pl[(size_t)c * RGT + rg];
    }
    float M = mc[0];
#pragma unroll
    for (int c = 1; c < NCH; ++c) M = fmaxf(M, mc[c]);
    float L = 0.f, w[NCH];
#pragma unroll
    for (int c = 0; c < NCH; ++c) { w[c] = expf(mc[c] - M); L += w[c] * lc[c]; }

    float4 o = make_float4(0.f, 0.f, 0.f, 0.f);
#pragma unroll
    for (int c = 0; c < NCH; ++c) {
        float4 v = ((const float4*)(po + ((size_t)c * RGT + rg) * HD))[d4];
        o.x += w[c] * v.x; o.y += w[c] * v.y; o.z += w[c] * v.z; o.w += w[c] * v.w;
    }
    const float inv = 1.f / L;
    const int b = rg / (NH * SEQ);
    const int h = (rg / SEQ) % NH;
    const int row = rg % SEQ;
    float4* op = (float4*)(attn + ((size_t)(b * SEQ + row)) * D + h * HD);
    op[d4] = make_float4(o.x * inv, o.y * inv, o.z * inv, o.w * inv);
}

// ---------------------------------------------------------------------------
// Kernel 3 (fallback): single-pass flash attention, one wave per 64 q rows.
// ---------------------------------------------------------------------------
__global__ __launch_bounds__(64) void k_attn(
    const float* __restrict__ qkv, float* __restrict__ out)
{
    const int bid = blockIdx.x;
    const int qb = bid & 7;
    const int h = (bid >> 3) % NH;
    const int b = bid / (8 * NH);
    const int row = qb * 64 + threadIdx.x;

    const float* base = qkv + (size_t)(b * SEQ) * D3 + h * HD;
    const float4* qp = (const float4*)(base + (size_t)row * D3);

    float4 q4[16], o4[16];
#pragma unroll
    for (int dc = 0; dc < 16; ++dc) {
        float4 qv = qp[dc];
        q4[dc] = make_float4(qv.x * 0.125f, qv.y * 0.125f, qv.z * 0.125f, qv.w * 0.125f);
        o4[dc] = make_float4(0.f, 0.f, 0.f, 0.f);
    }
    float m = -INFINITY, l = 0.f;

    for (int j0 = 0; j0 < SEQ; j0 += 16) {
        float s[16];
#pragma unroll
        for (int jj = 0; jj < 16; ++jj) {
            const float4* kp = (const float4*)(base + (size_t)(j0 + jj) * D3 + D);
            float acc = 0.f;
#pragma unroll
            for (int dc = 0; dc < 16; ++dc) {
                float4 kv = kp[dc];
                acc += q4[dc].x * kv.x + q4[dc].y * kv.y + q4[dc].z * kv.z + q4[dc].w * kv.w;
            }
            s[jj] = acc;
        }
        float mx = m;
#pragma unroll
        for (int jj = 0; jj < 16; ++jj) mx = fmaxf(mx, s[jj]);
        const float corr = expf(m - mx);
        m = mx;
        float sum = 0.f;
#pragma unroll
        for (int jj = 0; jj < 16; ++jj) { s[jj] = expf(s[jj] - m); sum += s[jj]; }
        l = l * corr + sum;
#pragma unroll
        for (int dc = 0; dc < 16; ++dc) {
            o4[dc].x *= corr; o4[dc].y *= corr; o4[dc].z *= corr; o4[dc].w *= corr;
        }
#pragma unroll
        for (int jj = 0; jj < 16; ++jj) {
            const float sj = s[jj];
            const float4* vp = (const float4*)(base + (size_t)(j0 + jj) * D3 + 2 * D);
#pragma unroll
            for (int dc = 0; dc < 16; ++dc) {
                float4 vv = vp[dc];
                o4[dc].x += sj * vv.x; o4[dc].y += sj * vv.y;
                o4[dc].z += sj * vv.z; o4[dc].w += sj * vv.w;
            }
        }
    }
    const float inv = 1.f / l;
    float4* op = (float4*)(out + (size_t)(b * SEQ + row) * D + h * HD);
#pragma unroll
    for (int dc = 0; dc < 16; ++dc) {
        op[dc] = make_float4(o4[dc].x * inv, o4[dc].y * inv, o4[dc].z * inv, o4[dc].w * inv);
    }
}

// ---------------------------------------------------------------------------
extern "C" void kernel_launch(void* const* d_in, const int* in_sizes, int n_in,
                              void* d_out, int out_size, void* d_ws, size_t ws_size,
                              hipStream_t stream)
{
    const float* x      = (const float*)d_in[0];
    const float* W_qkv  = (const float*)d_in[1];
    const float* b_qkv  = (const float*)d_in[2];
    const float* W_gate = (const float*)d_in[3];
    const float* b_gate = (const float*)d_in[4];
    const float* A      = (const float*)d_in[5];
    const float* B_lora = (const float*)d_in[6];
    const float* W_proj = (const float*)d_in[7];
    const float* b_proj = (const float*)d_in[8];
    float* out = (float*)d_out;

    // workspace layout (floats)
    float* qkv  = (float*)d_ws;                        // T * 3D
    float* attn = qkv + (size_t)TT * D3;               // T * D
    float* vl   = attn + (size_t)TT * D;               // T * 32
    int*   idx2 = (int*)(vl + (size_t)TT * 32);        // T * 2
    float* po   = (float*)(idx2 + (size_t)TT * 2);     // NCH * RGT * HD
    float* pm   = po + (size_t)NCH * RGT * HD;         // NCH * RGT
    float* pl   = pm + (size_t)NCH * RGT;              // NCH * RGT
    const size_t need_bytes = (size_t)(pl + (size_t)NCH * RGT - (float*)d_ws) * 4;
    const bool use_split = ws_size >= need_bytes;

    // 1. router + LoRA down
    k_router<<<TT, 64, 0, stream>>>(x, W_gate, b_gate, A, vl, idx2);

    // 2. QKV GEMM + bias + fused LoRA up
    {
        dim3 grid(D3 / BN, TT / BM);
        k_gemm_nt<true><<<grid, 256, 0, stream>>>(x, W_qkv, b_qkv, qkv,
                                                  TT, D3, D, vl, idx2, B_lora);
    }

    // 3. attention
    if (use_split) {
        k_attn_split<<<B_SZ * NH * 8 * NCH, 64, 0, stream>>>(qkv, po, pm, pl);
        k_attn_combine<<<RGT * 16 / 256, 256, 0, stream>>>(po, pm, pl, attn);
    } else {
        k_attn<<<B_SZ * NH * 8, 64, 0, stream>>>(qkv, attn);
    }

    // 4. output projection
    {
        dim3 grid(D / BN, TT / BM);
        k_gemm_nt<false><<<grid, 256, 0, stream>>>(attn, W_proj, b_proj, out,
                                                   TT, D, D, nullptr, nullptr, nullptr);
    }
}

// Round 3
// 610.727 us; speedup vs baseline: 2.3100x; 1.3995x over previous
//
#include <hip/hip_runtime.h>
#include <hip/hip_bf16.h>

// Problem constants
#define B_SZ 8
#define SEQ 512
#define D 768
#define D3 2304
#define NH 12
#define HD 64
#define NE 8
#define RANK 16
#define TT (B_SZ * SEQ)           // 4096 tokens
#define SCALING 2.0f              // ALPHA / RANK = 32/16
#define NCH 4                     // KV chunks for split attention
#define KVC (SEQ / NCH)           // 128 KV rows per chunk
#define RGT (B_SZ * NH * SEQ)     // 49152 global attention rows
#define KE 2304                   // extended K = 3 * 768 (bf16x3 split)

typedef __attribute__((ext_vector_type(8))) short bh8;
typedef __attribute__((ext_vector_type(4))) float fx4;

__device__ __forceinline__ unsigned short f2bf_rne(float x) {
    unsigned u = __float_as_uint(x);
    unsigned r = (u + 0x7FFFu + ((u >> 16) & 1u)) >> 16;
    return (unsigned short)r;
}
__device__ __forceinline__ float bf2f(unsigned short b) {
    return __uint_as_float(((unsigned)b) << 16);
}
__device__ __forceinline__ float dot4(float4 a, float4 b) {
    return a.x * b.x + a.y * b.y + a.z * b.z + a.w * b.w;
}
__device__ __forceinline__ void load_lds16(const void* g, void* l) {
    __builtin_amdgcn_global_load_lds(
        (const __attribute__((address_space(1))) unsigned int*)g,
        (__attribute__((address_space(3))) unsigned int*)l,
        16, 0, 0);
}

// ---------------------------------------------------------------------------
// bf16x3 split conversion: in [M][768] fp32 -> out [M][2304] bf16.
// A-layout: [hi | hi | lo]; B-layout: [hi | lo | hi].
// ---------------------------------------------------------------------------
template <bool ALAY>
__global__ __launch_bounds__(256) void k_convert(
    const float* __restrict__ in, unsigned short* __restrict__ out, int M)
{
    const int gid = blockIdx.x * 256 + threadIdx.x;
    if (gid >= M * 192) return;
    const int r = gid / 192;
    const int c4 = gid - r * 192;
    const float4 v = ((const float4*)(in + (size_t)r * D))[c4];
    ushort4 hi, lo;
    hi.x = f2bf_rne(v.x); hi.y = f2bf_rne(v.y);
    hi.z = f2bf_rne(v.z); hi.w = f2bf_rne(v.w);
    lo.x = f2bf_rne(v.x - bf2f(hi.x)); lo.y = f2bf_rne(v.y - bf2f(hi.y));
    lo.z = f2bf_rne(v.z - bf2f(hi.z)); lo.w = f2bf_rne(v.w - bf2f(hi.w));
    ushort4* row = (ushort4*)(out + (size_t)r * D3);
    row[c4] = hi;
    row[c4 + 192] = ALAY ? hi : lo;
    row[c4 + 384] = ALAY ? lo : hi;
}

// ---------------------------------------------------------------------------
// Kernel 1: router (softmax gate, top-2) + LoRA down (fp32, weight folded).
// One wave per token.
// ---------------------------------------------------------------------------
__global__ __launch_bounds__(64) void k_router(
    const float* __restrict__ x, const float* __restrict__ Wg,
    const float* __restrict__ bg, const float* __restrict__ A,
    float* __restrict__ vlora, int* __restrict__ idx2)
{
    const int t = blockIdx.x;
    const int l = threadIdx.x;
    const float* xr = x + (size_t)t * D;

    float xv[12];
#pragma unroll
    for (int i = 0; i < 12; ++i) xv[i] = xr[l + 64 * i];

    float p[NE];
#pragma unroll
    for (int e = 0; e < NE; ++e) {
        const float* w = Wg + (size_t)e * D;
        float s = 0.f;
#pragma unroll
        for (int i = 0; i < 12; ++i) s += xv[i] * w[l + 64 * i];
#pragma unroll
        for (int off = 32; off; off >>= 1) s += __shfl_xor(s, off);
        p[e] = s + bg[e];
    }
    float mx = p[0];
#pragma unroll
    for (int e = 1; e < NE; ++e) mx = fmaxf(mx, p[e]);
    float den = 0.f;
#pragma unroll
    for (int e = 0; e < NE; ++e) { p[e] = expf(p[e] - mx); den += p[e]; }
    int i0 = 0;
#pragma unroll
    for (int e = 1; e < NE; ++e) if (p[e] > p[i0]) i0 = e;
    int i1 = (i0 == 0) ? 1 : 0;
#pragma unroll
    for (int e = 0; e < NE; ++e) if (e != i1 && e != i0 && p[e] > p[i1]) i1 = e;
    const float w0 = p[i0] / den * SCALING;
    const float w1 = p[i1] / den * SCALING;
    if (l == 0) { idx2[2 * t] = i0; idx2[2 * t + 1] = i1; }

#pragma unroll
    for (int j = 0; j < 2; ++j) {
        const int e = j ? i1 : i0;
        const float wj = j ? w1 : w0;
        const float* Ae = A + (size_t)e * RANK * D;
#pragma unroll
        for (int r = 0; r < RANK; ++r) {
            const float* a = Ae + (size_t)r * D;
            float s = 0.f;
#pragma unroll
            for (int i = 0; i < 12; ++i) s += xv[i] * a[l + 64 * i];
#pragma unroll
            for (int off = 32; off; off >>= 1) s += __shfl_xor(s, off);
            if (l == 0) vlora[t * 32 + j * 16 + r] = s * wj;
        }
    }
}

// ---------------------------------------------------------------------------
// Kernel 2: bf16 MFMA GEMM (m97 structure).  C[m][n] = sum_k Ae[m][k]*Be[n][k]
// + bias[n] (+ fp32 LoRA-up epilogue).  Tile (2*FM*16) x (2*FN*16), BK=32,
// 4 waves (2x2), global_load_lds(16B) staging, 2 barriers per K-step.
// ---------------------------------------------------------------------------
template <int FM, int FN, bool LORA>
__global__ __launch_bounds__(256) void k_gemm_mfma(
    const unsigned short* __restrict__ Ae, const unsigned short* __restrict__ Be,
    const float* __restrict__ bias, float* __restrict__ C,
    int M, int N, int K2,
    const float* __restrict__ vlp, const int* __restrict__ idx2,
    const float* __restrict__ Bup)
{
    constexpr int BM = 2 * FM * 16;
    constexpr int BN = 2 * FN * 16;
    constexpr int ISS_A = BM / 64;
    constexpr int ISS_B = BN / 64;
    __shared__ __align__(16) unsigned short As[BM * 32];
    __shared__ __align__(16) unsigned short Bs[BN * 32];

    const int tid = threadIdx.x;
    const int lane = tid & 63;
    const int wv = tid >> 6;            // wave 0..3
    const int wr = wv >> 1, wc = wv & 1;
    const int m0 = blockIdx.y * BM;
    const int n0 = blockIdx.x * BN;

    fx4 acc[FM][FN] = {};

    const int arow = wv * 16 + (lane >> 2);   // staging row within 64-row issue
    const int acol = (lane & 3) * 8;          // staging col (bf16 elems)
    const int frow = lane & 15;
    const int fk = (lane >> 4) * 8;

    for (int k0 = 0; k0 < K2; k0 += 32) {
#pragma unroll
        for (int i = 0; i < ISS_A; ++i) {
            const unsigned short* src = Ae + (size_t)(m0 + i * 64 + arow) * K2 + k0 + acol;
            load_lds16(src, (char*)As + i * 4096 + wv * 1024);
        }
#pragma unroll
        for (int i = 0; i < ISS_B; ++i) {
            const unsigned short* src = Be + (size_t)(n0 + i * 64 + arow) * K2 + k0 + acol;
            load_lds16(src, (char*)Bs + i * 4096 + wv * 1024);
        }
        __syncthreads();
        bh8 afr[FM], bfr[FN];
#pragma unroll
        for (int i = 0; i < FM; ++i)
            afr[i] = *(const bh8*)&As[(wr * FM * 16 + i * 16 + frow) * 32 + fk];
#pragma unroll
        for (int j = 0; j < FN; ++j)
            bfr[j] = *(const bh8*)&Bs[(wc * FN * 16 + j * 16 + frow) * 32 + fk];
#pragma unroll
        for (int i = 0; i < FM; ++i)
#pragma unroll
            for (int j = 0; j < FN; ++j)
                acc[i][j] = __builtin_amdgcn_mfma_f32_16x16x32_bf16(
                    afr[i], bfr[j], acc[i][j], 0, 0, 0);
        __syncthreads();
    }

    // epilogue: C/D layout col = lane&15, row = (lane>>4)*4 + reg
    const int col = lane & 15;
    const int rbase = (lane >> 4) * 4;
#pragma unroll
    for (int i = 0; i < FM; ++i) {
#pragma unroll
        for (int r = 0; r < 4; ++r) {
            const int m = m0 + wr * FM * 16 + i * 16 + rbase + r;
            int e0 = 0, e1 = 0;
            float4 vv4[8];
            if (LORA) {
                e0 = idx2[2 * m]; e1 = idx2[2 * m + 1];
                const float4* vp = (const float4*)(vlp + (size_t)m * 32);
#pragma unroll
                for (int q = 0; q < 8; ++q) vv4[q] = vp[q];
            }
#pragma unroll
            for (int j = 0; j < FN; ++j) {
                const int n = n0 + wc * FN * 16 + j * 16 + col;
                float c = acc[i][j][r] + bias[n];
                if (LORA) {
                    const float4* u0 = (const float4*)(Bup + ((size_t)e0 * D3 + n) * RANK);
                    const float4* u1 = (const float4*)(Bup + ((size_t)e1 * D3 + n) * RANK);
                    float s = 0.f;
#pragma unroll
                    for (int q = 0; q < 4; ++q) s += dot4(vv4[q], u0[q]);
#pragma unroll
                    for (int q = 0; q < 4; ++q) s += dot4(vv4[4 + q], u1[q]);
                    c += s;
                }
                C[(size_t)m * N + n] = c;
            }
        }
    }
}

// ---------------------------------------------------------------------------
// Kernel 3a: split-KV flash attention (fp32). One wave per (b,h,qblock,chunk).
// ---------------------------------------------------------------------------
__global__ __launch_bounds__(64) void k_attn_split(
    const float* __restrict__ qkv, float* __restrict__ po,
    float* __restrict__ pm, float* __restrict__ pl)
{
    const int bid = blockIdx.x;
    const int c = bid & (NCH - 1);
    const int qb = (bid >> 2) & 7;
    const int h = (bid >> 5) % NH;
    const int b = bid / (32 * NH);
    const int row = qb * 64 + threadIdx.x;
    const int rg = (b * NH + h) * SEQ + row;

    const float* base = qkv + (size_t)(b * SEQ) * D3 + h * HD;
    const float4* qp = (const float4*)(base + (size_t)row * D3);

    float4 q4[16], o4[16];
#pragma unroll
    for (int dc = 0; dc < 16; ++dc) {
        float4 qv = qp[dc];
        q4[dc] = make_float4(qv.x * 0.125f, qv.y * 0.125f, qv.z * 0.125f, qv.w * 0.125f);
        o4[dc] = make_float4(0.f, 0.f, 0.f, 0.f);
    }
    float m = -INFINITY, l = 0.f;

    const int j_lo = c * KVC, j_hi = j_lo + KVC;
    for (int j0 = j_lo; j0 < j_hi; j0 += 16) {
        float s[16];
#pragma unroll
        for (int jj = 0; jj < 16; ++jj) {
            const float4* kp = (const float4*)(base + (size_t)(j0 + jj) * D3 + D);
            float acc = 0.f;
#pragma unroll
            for (int dc = 0; dc < 16; ++dc) {
                float4 kv = kp[dc];
                acc += q4[dc].x * kv.x + q4[dc].y * kv.y + q4[dc].z * kv.z + q4[dc].w * kv.w;
            }
            s[jj] = acc;
        }
        float mx = m;
#pragma unroll
        for (int jj = 0; jj < 16; ++jj) mx = fmaxf(mx, s[jj]);
        const float corr = expf(m - mx);
        m = mx;
        float sum = 0.f;
#pragma unroll
        for (int jj = 0; jj < 16; ++jj) { s[jj] = expf(s[jj] - m); sum += s[jj]; }
        l = l * corr + sum;
#pragma unroll
        for (int dc = 0; dc < 16; ++dc) {
            o4[dc].x *= corr; o4[dc].y *= corr; o4[dc].z *= corr; o4[dc].w *= corr;
        }
#pragma unroll
        for (int jj = 0; jj < 16; ++jj) {
            const float sj = s[jj];
            const float4* vp = (const float4*)(base + (size_t)(j0 + jj) * D3 + 2 * D);
#pragma unroll
            for (int dc = 0; dc < 16; ++dc) {
                float4 vv = vp[dc];
                o4[dc].x += sj * vv.x; o4[dc].y += sj * vv.y;
                o4[dc].z += sj * vv.z; o4[dc].w += sj * vv.w;
            }
        }
    }
    float4* op = (float4*)(po + ((size_t)c * RGT + rg) * HD);
#pragma unroll
    for (int dc = 0; dc < 16; ++dc) op[dc] = o4[dc];
    pm[(size_t)c * RGT + rg] = m;
    pl[(size_t)c * RGT + rg] = l;
}

// ---------------------------------------------------------------------------
// Kernel 3b: combine partials. One thread per (row, float4-column).
// ---------------------------------------------------------------------------
__global__ __launch_bounds__(256) void k_attn_combine(
    const float* __restrict__ po, const float* __restrict__ pm,
    const float* __restrict__ pl, float* __restrict__ attn)
{
    const int gid = blockIdx.x * 256 + threadIdx.x;
    const int rg = gid >> 4;
    const int d4 = gid & 15;

    float mc[NCH], lc[NCH];
#pragma unroll
    for (int c = 0; c < NCH; ++c) {
        mc[c] = pm[(size_t)c * RGT + rg];
        lc[c] = pl[(size_t)c * RGT + rg];
    }
    float M = mc[0];
#pragma unroll
    for (int c = 1; c < NCH; ++c) M = fmaxf(M, mc[c]);
    float L = 0.f, w[NCH];
#pragma unroll
    for (int c = 0; c < NCH; ++c) { w[c] = expf(mc[c] - M); L += w[c] * lc[c]; }

    float4 o = make_float4(0.f, 0.f, 0.f, 0.f);
#pragma unroll
    for (int c = 0; c < NCH; ++c) {
        float4 v = ((const float4*)(po + ((size_t)c * RGT + rg) * HD))[d4];
        o.x += w[c] * v.x; o.y += w[c] * v.y; o.z += w[c] * v.z; o.w += w[c] * v.w;
    }
    const float inv = 1.f / L;
    const int b = rg / (NH * SEQ);
    const int h = (rg / SEQ) % NH;
    const int row = rg % SEQ;
    float4* op = (float4*)(attn + ((size_t)(b * SEQ + row)) * D + h * HD);
    op[d4] = make_float4(o.x * inv, o.y * inv, o.z * inv, o.w * inv);
}

// ---------------------------------------------------------------------------
extern "C" void kernel_launch(void* const* d_in, const int* in_sizes, int n_in,
                              void* d_out, int out_size, void* d_ws, size_t ws_size,
                              hipStream_t stream)
{
    const float* x      = (const float*)d_in[0];
    const float* W_qkv  = (const float*)d_in[1];
    const float* b_qkv  = (const float*)d_in[2];
    const float* W_gate = (const float*)d_in[3];
    const float* b_gate = (const float*)d_in[4];
    const float* A      = (const float*)d_in[5];
    const float* B_lora = (const float*)d_in[6];
    const float* W_proj = (const float*)d_in[7];
    const float* b_proj = (const float*)d_in[8];
    float* out = (float*)d_out;

    // workspace layout (floats), ~103 MB total (fits: round-1 used the same)
    // region B is time-shared: {Xe,Wqe} -> {po,pm,pl} -> {Ae2,Wpe}
    const size_t REGB = (size_t)NCH * RGT * HD + 2 * (size_t)NCH * RGT; // 12,976,128
    float* qkv  = (float*)d_ws;                        // TT * D3
    float* regB = qkv + (size_t)TT * D3;
    float* attn = regB + REGB;                         // TT * D
    float* vl   = attn + (size_t)TT * D;               // TT * 32
    int*   idx2 = (int*)(vl + (size_t)TT * 32);        // TT * 2

    unsigned short* Xe  = (unsigned short*)regB;       // TT x KE bf16
    unsigned short* Wqe = Xe + (size_t)TT * KE;        // D3 x KE bf16
    float* po = regB;                                  // NCH*RGT*HD
    float* pm = po + (size_t)NCH * RGT * HD;
    float* pl = pm + (size_t)NCH * RGT;
    unsigned short* Ae2 = (unsigned short*)regB;       // TT x KE bf16
    unsigned short* Wpe = Ae2 + (size_t)TT * KE;       // D x KE bf16

    // 1. bf16x3 conversions + router/LoRA-down
    k_convert<true ><<<(TT * 192 + 255) / 256, 256, 0, stream>>>(x, Xe, TT);
    k_convert<false><<<(D3 * 192 + 255) / 256, 256, 0, stream>>>(W_qkv, Wqe, D3);
    k_router<<<TT, 64, 0, stream>>>(x, W_gate, b_gate, A, vl, idx2);

    // 2. QKV GEMM (bf16x3 MFMA) + bias + fp32 LoRA-up epilogue
    {
        dim3 grid(D3 / 128, TT / 128);
        k_gemm_mfma<4, 4, true><<<grid, 256, 0, stream>>>(
            Xe, Wqe, b_qkv, qkv, TT, D3, KE, vl, idx2, B_lora);
    }

    // 3. attention (split-KV + combine)
    k_attn_split<<<B_SZ * NH * 8 * NCH, 64, 0, stream>>>(qkv, po, pm, pl);
    k_attn_combine<<<RGT * 16 / 256, 256, 0, stream>>>(po, pm, pl, attn);

    // 4. output projection (bf16x3 MFMA)
    k_convert<true ><<<(TT * 192 + 255) / 256, 256, 0, stream>>>(attn, Ae2, TT);
    k_convert<false><<<(D * 192 + 255) / 256, 256, 0, stream>>>(W_proj, Wpe, D);
    {
        dim3 grid(D / 128, TT / 64);
        k_gemm_mfma<2, 4, false><<<grid, 256, 0, stream>>>(
            Ae2, Wpe, b_proj, out, TT, D, KE, nullptr, nullptr, nullptr);
    }
}

// Round 4
// 354.986 us; speedup vs baseline: 3.9743x; 1.7204x over previous
//
#include <hip/hip_runtime.h>
#include <hip/hip_bf16.h>

// Problem constants
#define B_SZ 8
#define SEQ 512
#define D 768
#define D3 2304
#define NH 12
#define HD 64
#define NE 8
#define RANK 16
#define TT (B_SZ * SEQ)           // 4096 tokens
#define SCALING 2.0f              // ALPHA / RANK = 32/16
#define KE 2304                   // extended K = 3 * 768 (bf16x3 split)
#define EK 192                    // extended head dim = 3 * 64
#define NBH (B_SZ * NH)           // 96

typedef __attribute__((ext_vector_type(8))) short bh8;
typedef __attribute__((ext_vector_type(4))) float fx4;

__device__ __forceinline__ unsigned short f2bf_rne(float x) {
    unsigned u = __float_as_uint(x);
    unsigned r = (u + 0x7FFFu + ((u >> 16) & 1u)) >> 16;
    return (unsigned short)r;
}
__device__ __forceinline__ float bf2f(unsigned short b) {
    return __uint_as_float(((unsigned)b) << 16);
}
__device__ __forceinline__ float dot4(float4 a, float4 b) {
    return a.x * b.x + a.y * b.y + a.z * b.z + a.w * b.w;
}
__device__ __forceinline__ void load_lds16(const void* g, void* l) {
    __builtin_amdgcn_global_load_lds(
        (const __attribute__((address_space(1))) unsigned int*)g,
        (__attribute__((address_space(3))) unsigned int*)l,
        16, 0, 0);
}

// ---------------------------------------------------------------------------
// bf16x3 split conversion: in [M][768] fp32 -> out [M][2304] bf16.
// A-layout: [hi | hi | lo]; B-layout: [hi | lo | hi].
// ---------------------------------------------------------------------------
template <bool ALAY>
__global__ __launch_bounds__(256) void k_convert(
    const float* __restrict__ in, unsigned short* __restrict__ out, int M)
{
    const int gid = blockIdx.x * 256 + threadIdx.x;
    if (gid >= M * 192) return;
    const int r = gid / 192;
    const int c4 = gid - r * 192;
    const float4 v = ((const float4*)(in + (size_t)r * D))[c4];
    ushort4 hi, lo;
    hi.x = f2bf_rne(v.x); hi.y = f2bf_rne(v.y);
    hi.z = f2bf_rne(v.z); hi.w = f2bf_rne(v.w);
    lo.x = f2bf_rne(v.x - bf2f(hi.x)); lo.y = f2bf_rne(v.y - bf2f(hi.y));
    lo.z = f2bf_rne(v.z - bf2f(hi.z)); lo.w = f2bf_rne(v.w - bf2f(hi.w));
    ushort4* row = (ushort4*)(out + (size_t)r * D3);
    row[c4] = hi;
    row[c4 + 192] = ALAY ? hi : lo;
    row[c4 + 384] = ALAY ? lo : hi;
}

// ---------------------------------------------------------------------------
// Kernel 1: router (softmax gate, top-2) + LoRA down (fp32, weight folded).
// ---------------------------------------------------------------------------
__global__ __launch_bounds__(64) void k_router(
    const float* __restrict__ x, const float* __restrict__ Wg,
    const float* __restrict__ bg, const float* __restrict__ A,
    float* __restrict__ vlora, int* __restrict__ idx2)
{
    const int t = blockIdx.x;
    const int l = threadIdx.x;
    const float* xr = x + (size_t)t * D;

    float xv[12];
#pragma unroll
    for (int i = 0; i < 12; ++i) xv[i] = xr[l + 64 * i];

    float p[NE];
#pragma unroll
    for (int e = 0; e < NE; ++e) {
        const float* w = Wg + (size_t)e * D;
        float s = 0.f;
#pragma unroll
        for (int i = 0; i < 12; ++i) s += xv[i] * w[l + 64 * i];
#pragma unroll
        for (int off = 32; off; off >>= 1) s += __shfl_xor(s, off);
        p[e] = s + bg[e];
    }
    float mx = p[0];
#pragma unroll
    for (int e = 1; e < NE; ++e) mx = fmaxf(mx, p[e]);
    float den = 0.f;
#pragma unroll
    for (int e = 0; e < NE; ++e) { p[e] = expf(p[e] - mx); den += p[e]; }
    int i0 = 0;
#pragma unroll
    for (int e = 1; e < NE; ++e) if (p[e] > p[i0]) i0 = e;
    int i1 = (i0 == 0) ? 1 : 0;
#pragma unroll
    for (int e = 0; e < NE; ++e) if (e != i1 && e != i0 && p[e] > p[i1]) i1 = e;
    const float w0 = p[i0] / den * SCALING;
    const float w1 = p[i1] / den * SCALING;
    if (l == 0) { idx2[2 * t] = i0; idx2[2 * t + 1] = i1; }

#pragma unroll
    for (int j = 0; j < 2; ++j) {
        const int e = j ? i1 : i0;
        const float wj = j ? w1 : w0;
        const float* Ae = A + (size_t)e * RANK * D;
#pragma unroll
        for (int r = 0; r < RANK; ++r) {
            const float* a = Ae + (size_t)r * D;
            float s = 0.f;
#pragma unroll
            for (int i = 0; i < 12; ++i) s += xv[i] * a[l + 64 * i];
#pragma unroll
            for (int off = 32; off; off >>= 1) s += __shfl_xor(s, off);
            if (l == 0) vlora[t * 32 + j * 16 + r] = s * wj;
        }
    }
}

// ---------------------------------------------------------------------------
// Kernel 2: bf16 MFMA GEMM (m97 structure), optional fp32 LoRA-up epilogue.
// ---------------------------------------------------------------------------
template <int FM, int FN, bool LORA>
__global__ __launch_bounds__(256) void k_gemm_mfma(
    const unsigned short* __restrict__ Ae, const unsigned short* __restrict__ Be,
    const float* __restrict__ bias, float* __restrict__ C,
    int M, int N, int K2,
    const float* __restrict__ vlp, const int* __restrict__ idx2,
    const float* __restrict__ Bup)
{
    constexpr int BM = 2 * FM * 16;
    constexpr int BN = 2 * FN * 16;
    constexpr int ISS_A = BM / 64;
    constexpr int ISS_B = BN / 64;
    __shared__ __align__(16) unsigned short As[BM * 32];
    __shared__ __align__(16) unsigned short Bs[BN * 32];

    const int tid = threadIdx.x;
    const int lane = tid & 63;
    const int wv = tid >> 6;
    const int wr = wv >> 1, wc = wv & 1;
    const int m0 = blockIdx.y * BM;
    const int n0 = blockIdx.x * BN;

    fx4 acc[FM][FN] = {};

    const int arow = wv * 16 + (lane >> 2);
    const int acol = (lane & 3) * 8;
    const int frow = lane & 15;
    const int fk = (lane >> 4) * 8;

    for (int k0 = 0; k0 < K2; k0 += 32) {
#pragma unroll
        for (int i = 0; i < ISS_A; ++i) {
            const unsigned short* src = Ae + (size_t)(m0 + i * 64 + arow) * K2 + k0 + acol;
            load_lds16(src, (char*)As + i * 4096 + wv * 1024);
        }
#pragma unroll
        for (int i = 0; i < ISS_B; ++i) {
            const unsigned short* src = Be + (size_t)(n0 + i * 64 + arow) * K2 + k0 + acol;
            load_lds16(src, (char*)Bs + i * 4096 + wv * 1024);
        }
        __syncthreads();
        bh8 afr[FM], bfr[FN];
#pragma unroll
        for (int i = 0; i < FM; ++i)
            afr[i] = *(const bh8*)&As[(wr * FM * 16 + i * 16 + frow) * 32 + fk];
#pragma unroll
        for (int j = 0; j < FN; ++j)
            bfr[j] = *(const bh8*)&Bs[(wc * FN * 16 + j * 16 + frow) * 32 + fk];
#pragma unroll
        for (int i = 0; i < FM; ++i)
#pragma unroll
            for (int j = 0; j < FN; ++j)
                acc[i][j] = __builtin_amdgcn_mfma_f32_16x16x32_bf16(
                    afr[i], bfr[j], acc[i][j], 0, 0, 0);
        __syncthreads();
    }

    const int col = lane & 15;
    const int rbase = (lane >> 4) * 4;
#pragma unroll
    for (int i = 0; i < FM; ++i) {
#pragma unroll
        for (int r = 0; r < 4; ++r) {
            const int m = m0 + wr * FM * 16 + i * 16 + rbase + r;
            int e0 = 0, e1 = 0;
            float4 vv4[8];
            if (LORA) {
                e0 = idx2[2 * m]; e1 = idx2[2 * m + 1];
                const float4* vp = (const float4*)(vlp + (size_t)m * 32);
#pragma unroll
                for (int q = 0; q < 8; ++q) vv4[q] = vp[q];
            }
#pragma unroll
            for (int j = 0; j < FN; ++j) {
                const int n = n0 + wc * FN * 16 + j * 16 + col;
                float c = acc[i][j][r] + bias[n];
                if (LORA) {
                    const float4* u0 = (const float4*)(Bup + ((size_t)e0 * D3 + n) * RANK);
                    const float4* u1 = (const float4*)(Bup + ((size_t)e1 * D3 + n) * RANK);
                    float s = 0.f;
#pragma unroll
                    for (int q = 0; q < 4; ++q) s += dot4(vv4[q], u0[q]);
#pragma unroll
                    for (int q = 0; q < 4; ++q) s += dot4(vv4[4 + q], u1[q]);
                    c += s;
                }
                C[(size_t)m * N + n] = c;
            }
        }
    }
}

// ---------------------------------------------------------------------------
// Kernel 3a: Q/K conversion for MFMA attention.
// Qe[bh][s][192] = [q_hi | q_hi | q_lo] of q*0.125 ;  Ke = [k_hi | k_lo | k_hi].
// ---------------------------------------------------------------------------
__global__ __launch_bounds__(256) void k_qk_convert(
    const float* __restrict__ qkv, unsigned short* __restrict__ Qe,
    unsigned short* __restrict__ Ke)
{
    const int gid = blockIdx.x * 256 + threadIdx.x;   // NBH*512*16
    const int d4 = gid & 15;
    const int s = (gid >> 4) & 511;
    const int bh = gid >> 13;
    const int b = bh / NH, h = bh - b * NH;
    const size_t t = (size_t)b * SEQ + s;
    const float4 q = ((const float4*)(qkv + t * D3 + h * HD))[d4];
    const float4 k = ((const float4*)(qkv + t * D3 + D + h * HD))[d4];
    ushort4 qh, ql, kh, kl;
    float4 qs = make_float4(q.x * 0.125f, q.y * 0.125f, q.z * 0.125f, q.w * 0.125f);
    qh.x = f2bf_rne(qs.x); qh.y = f2bf_rne(qs.y);
    qh.z = f2bf_rne(qs.z); qh.w = f2bf_rne(qs.w);
    ql.x = f2bf_rne(qs.x - bf2f(qh.x)); ql.y = f2bf_rne(qs.y - bf2f(qh.y));
    ql.z = f2bf_rne(qs.z - bf2f(qh.z)); ql.w = f2bf_rne(qs.w - bf2f(qh.w));
    kh.x = f2bf_rne(k.x); kh.y = f2bf_rne(k.y);
    kh.z = f2bf_rne(k.z); kh.w = f2bf_rne(k.w);
    kl.x = f2bf_rne(k.x - bf2f(kh.x)); kl.y = f2bf_rne(k.y - bf2f(kh.y));
    kl.z = f2bf_rne(k.z - bf2f(kh.z)); kl.w = f2bf_rne(k.w - bf2f(kh.w));
    ushort4* qrow = (ushort4*)(Qe + ((size_t)bh * SEQ + s) * EK);
    qrow[d4] = qh; qrow[16 + d4] = qh; qrow[32 + d4] = ql;
    ushort4* krow = (ushort4*)(Ke + ((size_t)bh * SEQ + s) * EK);
    krow[d4] = kh; krow[16 + d4] = kl; krow[32 + d4] = kh;
}

// ---------------------------------------------------------------------------
// Kernel 3b: V transpose to Vt[bh][d=64][s=512] bf16 (LDS transpose).
// ---------------------------------------------------------------------------
__global__ __launch_bounds__(256) void k_v_transpose(
    const float* __restrict__ qkv, unsigned short* __restrict__ Vt)
{
    __shared__ unsigned short T[64 * 72];
    const int bid = blockIdx.x;
    const int sb = bid & 7;
    const int bh = bid >> 3;
    const int b = bh / NH, h = bh - b * NH;
    const int tid = threadIdx.x;
    const int s0 = sb * 64;
    {
        const int ss = tid >> 2, cq = tid & 3;
        const float* src = qkv + ((size_t)(b * SEQ + s0 + ss)) * D3 + 2 * D + h * HD;
#pragma unroll
        for (int i = 0; i < 4; ++i) {
            float4 v = ((const float4*)src)[cq * 4 + i];
            ushort4 u;
            u.x = f2bf_rne(v.x); u.y = f2bf_rne(v.y);
            u.z = f2bf_rne(v.z); u.w = f2bf_rne(v.w);
            *(ushort4*)&T[ss * 72 + (cq * 4 + i) * 4] = u;
        }
    }
    __syncthreads();
    {
        const int d = tid >> 2, cs = tid & 3;
        __align__(16) unsigned short tmp[16];
#pragma unroll
        for (int j = 0; j < 16; ++j)
            tmp[j] = T[(cs * 16 + j) * 72 + d];
        unsigned short* dst = Vt + ((size_t)bh * HD + d) * SEQ + s0 + cs * 16;
        *(bh8*)dst = *(const bh8*)tmp;
        *(bh8*)(dst + 8) = *(const bh8*)(tmp + 8);
    }
}

// ---------------------------------------------------------------------------
// Kernel 3c: MFMA flash attention. 4 waves per block; block = (bh, 64-row
// Q-block); each wave owns 16 q rows. KV tiles of 64, K in bf16x3 (exact),
// P/V in bf16. Padded LDS (reg-staged) -> 2-way conflicts only.
// ---------------------------------------------------------------------------
__global__ __launch_bounds__(256) void k_attn_mfma(
    const unsigned short* __restrict__ Qe, const unsigned short* __restrict__ Ke,
    const unsigned short* __restrict__ Vt, float* __restrict__ attn)
{
    __shared__ __align__(16) unsigned short Ks[64 * 200];
    __shared__ __align__(16) unsigned short Vs[64 * 72];
    __shared__ __align__(16) unsigned short Ps[4 * 16 * 72];

    const int bid = blockIdx.x;
    const int qb = bid & 7;
    const int bh = bid >> 3;
    const int b = bh / NH, h = bh - b * NH;
    const int tid = threadIdx.x;
    const int lane = tid & 63;
    const int wv = tid >> 6;
    const int lg = lane >> 4;         // 0..3
    const int lr = lane & 15;         // 0..15
    const int q0 = qb * 64 + wv * 16;

    // Q A-fragments (6 k-chunks of 32), reused across all KV tiles
    bh8 qa[6];
    {
        const unsigned short* qrow = Qe + ((size_t)bh * SEQ + q0 + lr) * EK + lg * 8;
#pragma unroll
        for (int kc = 0; kc < 6; ++kc)
            qa[kc] = *(const bh8*)(qrow + kc * 32);
    }

    fx4 o[4] = {};
    float m4[4], l4[4];
#pragma unroll
    for (int r = 0; r < 4; ++r) { m4[r] = -INFINITY; l4[r] = 0.f; }

    const int sr = tid >> 2, sc = tid & 3;    // staging: row, chunk
    bh8 kreg[6], vreg[2];
    {
        const unsigned short* ksrc = Ke + ((size_t)bh * SEQ + sr) * EK + sc * 48;
#pragma unroll
        for (int j = 0; j < 6; ++j) kreg[j] = *(const bh8*)(ksrc + j * 8);
        const unsigned short* vsrc = Vt + ((size_t)bh * HD + sr) * SEQ + sc * 16;
#pragma unroll
        for (int j = 0; j < 2; ++j) vreg[j] = *(const bh8*)(vsrc + j * 8);
    }

    for (int kt = 0; kt < 8; ++kt) {
        __syncthreads();
#pragma unroll
        for (int j = 0; j < 6; ++j)
            *(bh8*)&Ks[sr * 200 + sc * 48 + j * 8] = kreg[j];
#pragma unroll
        for (int j = 0; j < 2; ++j)
            *(bh8*)&Vs[sr * 72 + sc * 16 + j * 8] = vreg[j];
        __syncthreads();
        if (kt < 7) {
            const int kv1 = (kt + 1) * 64;
            const unsigned short* ksrc = Ke + ((size_t)bh * SEQ + kv1 + sr) * EK + sc * 48;
#pragma unroll
            for (int j = 0; j < 6; ++j) kreg[j] = *(const bh8*)(ksrc + j * 8);
            const unsigned short* vsrc = Vt + ((size_t)bh * HD + sr) * SEQ + kv1 + sc * 16;
#pragma unroll
            for (int j = 0; j < 2; ++j) vreg[j] = *(const bh8*)(vsrc + j * 8);
        }

        // S = Q K^T (bf16x3 extended-K, exact)
        fx4 sf[4] = {};
#pragma unroll
        for (int kc = 0; kc < 6; ++kc) {
            bh8 kb[4];
#pragma unroll
            for (int j = 0; j < 4; ++j)
                kb[j] = *(const bh8*)&Ks[(j * 16 + lr) * 200 + kc * 32 + lg * 8];
#pragma unroll
            for (int j = 0; j < 4; ++j)
                sf[j] = __builtin_amdgcn_mfma_f32_16x16x32_bf16(qa[kc], kb[j], sf[j], 0, 0, 0);
        }

        // online softmax: rows lg*4+r, cols j*16+lr spread over 16-lane group
        float mx[4];
#pragma unroll
        for (int r = 0; r < 4; ++r)
            mx[r] = fmaxf(fmaxf(sf[0][r], sf[1][r]), fmaxf(sf[2][r], sf[3][r]));
#pragma unroll
        for (int off = 1; off < 16; off <<= 1)
#pragma unroll
            for (int r = 0; r < 4; ++r)
                mx[r] = fmaxf(mx[r], __shfl_xor(mx[r], off));
        float corr[4];
#pragma unroll
        for (int r = 0; r < 4; ++r) {
            const float mn = fmaxf(m4[r], mx[r]);
            corr[r] = expf(m4[r] - mn);
            m4[r] = mn;
        }
#pragma unroll
        for (int j = 0; j < 4; ++j)
#pragma unroll
            for (int r = 0; r < 4; ++r)
                sf[j][r] = expf(sf[j][r] - m4[r]);
        float rs[4];
#pragma unroll
        for (int r = 0; r < 4; ++r)
            rs[r] = (sf[0][r] + sf[1][r]) + (sf[2][r] + sf[3][r]);
#pragma unroll
        for (int off = 1; off < 16; off <<= 1)
#pragma unroll
            for (int r = 0; r < 4; ++r)
                rs[r] += __shfl_xor(rs[r], off);
#pragma unroll
        for (int r = 0; r < 4; ++r)
            l4[r] = l4[r] * corr[r] + rs[r];
#pragma unroll
        for (int j = 0; j < 4; ++j)
#pragma unroll
            for (int r = 0; r < 4; ++r)
                o[j][r] *= corr[r];

        // P -> per-wave LDS strip (bf16), reload as A-frags
        unsigned short* pw = Ps + wv * (16 * 72);
#pragma unroll
        for (int j = 0; j < 4; ++j)
#pragma unroll
            for (int r = 0; r < 4; ++r)
                pw[(lg * 4 + r) * 72 + j * 16 + lr] = f2bf_rne(sf[j][r]);

        // O += P V
#pragma unroll
        for (int kc = 0; kc < 2; ++kc) {
            bh8 pa = *(const bh8*)&pw[lr * 72 + kc * 32 + lg * 8];
            bh8 vb[4];
#pragma unroll
            for (int j = 0; j < 4; ++j)
                vb[j] = *(const bh8*)&Vs[(j * 16 + lr) * 72 + kc * 32 + lg * 8];
#pragma unroll
            for (int j = 0; j < 4; ++j)
                o[j] = __builtin_amdgcn_mfma_f32_16x16x32_bf16(pa, vb[j], o[j], 0, 0, 0);
        }
    }

    // epilogue
    float inv[4];
#pragma unroll
    for (int r = 0; r < 4; ++r) inv[r] = 1.f / l4[r];
    const int srow = b * SEQ + q0 + lg * 4;
#pragma unroll
    for (int j = 0; j < 4; ++j)
#pragma unroll
        for (int r = 0; r < 4; ++r)
            attn[(size_t)(srow + r) * D + h * HD + j * 16 + lr] = o[j][r] * inv[r];
}

// ---------------------------------------------------------------------------
extern "C" void kernel_launch(void* const* d_in, const int* in_sizes, int n_in,
                              void* d_out, int out_size, void* d_ws, size_t ws_size,
                              hipStream_t stream)
{
    const float* x      = (const float*)d_in[0];
    const float* W_qkv  = (const float*)d_in[1];
    const float* b_qkv  = (const float*)d_in[2];
    const float* W_gate = (const float*)d_in[3];
    const float* b_gate = (const float*)d_in[4];
    const float* A      = (const float*)d_in[5];
    const float* B_lora = (const float*)d_in[6];
    const float* W_proj = (const float*)d_in[7];
    const float* b_proj = (const float*)d_in[8];
    float* out = (float*)d_out;

    // workspace layout (~95 MB); regB time-shared across phases
    float* qkv  = (float*)d_ws;                        // TT*D3
    float* attn = qkv + (size_t)TT * D3;               // TT*D
    float* vl   = attn + (size_t)TT * D;               // TT*32
    int*   idx2 = (int*)(vl + (size_t)TT * 32);        // TT*2
    float* regB = (float*)(idx2 + (size_t)TT * 2);

    // phase A: bf16x3 operands for QKV GEMM
    unsigned short* Xe  = (unsigned short*)regB;       // TT x KE
    unsigned short* Wqe = Xe + (size_t)TT * KE;        // D3 x KE
    // phase B: attention operands
    unsigned short* Qe = (unsigned short*)regB;        // NBH x 512 x 192
    unsigned short* Ke = Qe + (size_t)NBH * SEQ * EK;
    unsigned short* Vt = Ke + (size_t)NBH * SEQ * EK;  // NBH x 64 x 512
    // phase C: proj operands
    unsigned short* Ae2 = (unsigned short*)regB;       // TT x KE
    unsigned short* Wpe = Ae2 + (size_t)TT * KE;       // D x KE

    // 1. conversions + router/LoRA-down
    k_convert<true ><<<(TT * 192 + 255) / 256, 256, 0, stream>>>(x, Xe, TT);
    k_convert<false><<<(D3 * 192 + 255) / 256, 256, 0, stream>>>(W_qkv, Wqe, D3);
    k_router<<<TT, 64, 0, stream>>>(x, W_gate, b_gate, A, vl, idx2);

    // 2. QKV GEMM (bf16x3 MFMA) + bias + fp32 LoRA-up epilogue
    {
        dim3 grid(D3 / 128, TT / 128);
        k_gemm_mfma<4, 4, true><<<grid, 256, 0, stream>>>(
            Xe, Wqe, b_qkv, qkv, TT, D3, KE, vl, idx2, B_lora);
    }

    // 3. attention: convert Q/K (bf16x3, scale folded) + transpose V, then MFMA flash
    k_qk_convert<<<NBH * SEQ * 16 / 256, 256, 0, stream>>>(qkv, Qe, Ke);
    k_v_transpose<<<NBH * 8, 256, 0, stream>>>(qkv, Vt);
    k_attn_mfma<<<NBH * 8, 256, 0, stream>>>(Qe, Ke, Vt, attn);

    // 4. output projection (bf16x3 MFMA)
    k_convert<true ><<<(TT * 192 + 255) / 256, 256, 0, stream>>>(attn, Ae2, TT);
    k_convert<false><<<(D * 192 + 255) / 256, 256, 0, stream>>>(W_proj, Wpe, D);
    {
        dim3 grid(D / 128, TT / 64);
        k_gemm_mfma<2, 4, false><<<grid, 256, 0, stream>>>(
            Ae2, Wpe, b_proj, out, TT, D, KE, nullptr, nullptr, nullptr);
    }
}

// Round 5
// 226.422 us; speedup vs baseline: 6.2309x; 1.5678x over previous
//
#include <hip/hip_runtime.h>
#include <hip/hip_bf16.h>

// Problem constants
#define B_SZ 8
#define SEQ 512
#define D 768
#define D3 2304
#define NH 12
#define HD 64
#define NE 8
#define RANK 16
#define TT (B_SZ * SEQ)           // 4096 tokens
#define SCALING 2.0f              // ALPHA / RANK = 32/16
#define KE 2304                   // 3 * 768 (bf16x3 split)
#define KQ 2560                   // 2304 + 2*128 (LoRA-up folded into K)
#define EK 192                    // extended head dim = 3 * 64
#define NBH (B_SZ * NH)           // 96

typedef __attribute__((ext_vector_type(8))) short bh8;
typedef __attribute__((ext_vector_type(4))) float fx4;

__device__ __forceinline__ unsigned short f2bf_rne(float x) {
    unsigned u = __float_as_uint(x);
    unsigned r = (u + 0x7FFFu + ((u >> 16) & 1u)) >> 16;
    return (unsigned short)r;
}
__device__ __forceinline__ float bf2f(unsigned short b) {
    return __uint_as_float(((unsigned)b) << 16);
}
__device__ __forceinline__ void load_lds16(const void* g, void* l) {
    __builtin_amdgcn_global_load_lds(
        (const __attribute__((address_space(1))) unsigned int*)g,
        (__attribute__((address_space(3))) unsigned int*)l,
        16, 0, 0);
}

// ---------------------------------------------------------------------------
// bf16x3 split conversion: in [M][768] fp32 -> first 2304 cols of out rows
// (row stride RS shorts). A-layout: [hi|hi|lo]; B-layout: [hi|lo|hi].
// ---------------------------------------------------------------------------
template <int RS, bool ALAY>
__global__ __launch_bounds__(256) void k_convert(
    const float* __restrict__ in, unsigned short* __restrict__ out, int M)
{
    const int gid = blockIdx.x * 256 + threadIdx.x;
    if (gid >= M * 192) return;
    const int r = gid / 192;
    const int c4 = gid - r * 192;
    const float4 v = ((const float4*)(in + (size_t)r * D))[c4];
    ushort4 hi, lo;
    hi.x = f2bf_rne(v.x); hi.y = f2bf_rne(v.y);
    hi.z = f2bf_rne(v.z); hi.w = f2bf_rne(v.w);
    lo.x = f2bf_rne(v.x - bf2f(hi.x)); lo.y = f2bf_rne(v.y - bf2f(hi.y));
    lo.z = f2bf_rne(v.z - bf2f(hi.z)); lo.w = f2bf_rne(v.w - bf2f(hi.w));
    ushort4* row = (ushort4*)(out + (size_t)r * RS);
    row[c4] = hi;
    row[c4 + 192] = ALAY ? hi : lo;
    row[c4 + 384] = ALAY ? lo : hi;
}

// ---------------------------------------------------------------------------
// B_lora tail fill: B2[n][2304 + e*16 + r] = B2[n][2432 + ...] = bf16(Bup[e][n][r])
// ---------------------------------------------------------------------------
__global__ __launch_bounds__(256) void k_blora(
    const float* __restrict__ Bup, unsigned short* __restrict__ B2)
{
    const int gid = blockIdx.x * 256 + threadIdx.x;
    if (gid >= D3 * 128) return;
    const int n = gid >> 7;
    const int p = gid & 127;
    const int e = p >> 4, r = p & 15;
    const unsigned short h = f2bf_rne(Bup[((size_t)e * D3 + n) * RANK + r]);
    B2[(size_t)n * KQ + 2304 + p] = h;
    B2[(size_t)n * KQ + 2432 + p] = h;
}

// ---------------------------------------------------------------------------
// Kernel 1: router (softmax gate, top-2) + LoRA down; writes the 256-entry
// bf16 tail [v_hi | v_lo] of A2 rows directly (dispatch weights + scaling
// folded, zeros elsewhere). One wave per token; per-lane predicated regs.
// ---------------------------------------------------------------------------
__global__ __launch_bounds__(64) void k_router(
    const float* __restrict__ x, const float* __restrict__ Wg,
    const float* __restrict__ bg, const float* __restrict__ A,
    unsigned short* __restrict__ A2)
{
    const int t = blockIdx.x;
    const int l = threadIdx.x;
    const float* xr = x + (size_t)t * D;

    float xv[12];
#pragma unroll
    for (int i = 0; i < 12; ++i) xv[i] = xr[l + 64 * i];

    float p[NE];
#pragma unroll
    for (int e = 0; e < NE; ++e) {
        const float* w = Wg + (size_t)e * D;
        float s = 0.f;
#pragma unroll
        for (int i = 0; i < 12; ++i) s += xv[i] * w[l + 64 * i];
#pragma unroll
        for (int off = 32; off; off >>= 1) s += __shfl_xor(s, off);
        p[e] = s + bg[e];
    }
    float mx = p[0];
#pragma unroll
    for (int e = 1; e < NE; ++e) mx = fmaxf(mx, p[e]);
    float den = 0.f;
#pragma unroll
    for (int e = 0; e < NE; ++e) { p[e] = expf(p[e] - mx); den += p[e]; }
    int i0 = 0;
#pragma unroll
    for (int e = 1; e < NE; ++e) if (p[e] > p[i0]) i0 = e;
    int i1 = (i0 == 0) ? 1 : 0;
#pragma unroll
    for (int e = 0; e < NE; ++e) if (e != i1 && e != i0 && p[e] > p[i1]) i1 = e;
    const float w0 = p[i0] / den * SCALING;
    const float w1 = p[i1] / den * SCALING;

    // per-lane tail registers (4 entries each, statically indexed)
    unsigned short tv0 = 0, tv1 = 0, tv2 = 0, tv3 = 0;
    const int base = 4 * l;

#pragma unroll
    for (int j = 0; j < 2; ++j) {
        const int e = j ? i1 : i0;
        const float wj = j ? w1 : w0;
        const float* Ae = A + (size_t)e * RANK * D;
#pragma unroll
        for (int r = 0; r < RANK; ++r) {
            const float* a = Ae + (size_t)r * D;
            float s = 0.f;
#pragma unroll
            for (int i = 0; i < 12; ++i) s += xv[i] * a[l + 64 * i];
#pragma unroll
            for (int off = 32; off; off >>= 1) s += __shfl_xor(s, off);
            const float val = s * wj;                  // all lanes hold val
            const unsigned short hi = f2bf_rne(val);
            const unsigned short lo = f2bf_rne(val - bf2f(hi));
            const int ph = e * 16 + r;                 // hi-section entry
            const int pl = ph + 128;                   // lo-section entry
            tv0 = (base + 0 == ph) ? hi : ((base + 0 == pl) ? lo : tv0);
            tv1 = (base + 1 == ph) ? hi : ((base + 1 == pl) ? lo : tv1);
            tv2 = (base + 2 == ph) ? hi : ((base + 2 == pl) ? lo : tv2);
            tv3 = (base + 3 == ph) ? hi : ((base + 3 == pl) ? lo : tv3);
        }
    }
    ushort4 tq; tq.x = tv0; tq.y = tv1; tq.z = tv2; tq.w = tv3;
    *(ushort4*)(A2 + (size_t)t * KQ + 2304 + base) = tq;
}

// ---------------------------------------------------------------------------
// Kernel 2: bf16 MFMA GEMM (m97 structure) + bias. XCD-swizzled grid.
// C[m][n] = sum_k Ae[m][k]*Be[n][k] + bias[n]. Tile (2*FM*16)x(2*FN*16), BK=32.
// ---------------------------------------------------------------------------
template <int FM, int FN>
__global__ __launch_bounds__(256) void k_gemm_mfma(
    const unsigned short* __restrict__ Ae, const unsigned short* __restrict__ Be,
    const float* __restrict__ bias, float* __restrict__ C,
    int N, int K2)
{
    constexpr int BM = 2 * FM * 16;
    constexpr int BN = 2 * FN * 16;
    constexpr int ISS_A = BM / 64;
    constexpr int ISS_B = BN / 64;
    __shared__ __align__(16) unsigned short As[BM * 32];
    __shared__ __align__(16) unsigned short Bs[BN * 32];

    // XCD-aware bijective swizzle (grid count divisible by 8)
    const int nwg = gridDim.x * gridDim.y;
    const int id = blockIdx.y * gridDim.x + blockIdx.x;
    const int cpx = nwg >> 3;
    const int swz = (id & 7) * cpx + (id >> 3);
    const int gx = swz % gridDim.x;
    const int gy = swz / gridDim.x;

    const int tid = threadIdx.x;
    const int lane = tid & 63;
    const int wv = tid >> 6;
    const int wr = wv >> 1, wc = wv & 1;
    const int m0 = gy * BM;
    const int n0 = gx * BN;

    fx4 acc[FM][FN] = {};

    const int arow = wv * 16 + (lane >> 2);
    const int acol = (lane & 3) * 8;
    const int frow = lane & 15;
    const int fk = (lane >> 4) * 8;

    for (int k0 = 0; k0 < K2; k0 += 32) {
#pragma unroll
        for (int i = 0; i < ISS_A; ++i) {
            const unsigned short* src = Ae + (size_t)(m0 + i * 64 + arow) * K2 + k0 + acol;
            load_lds16(src, (char*)As + i * 4096 + wv * 1024);
        }
#pragma unroll
        for (int i = 0; i < ISS_B; ++i) {
            const unsigned short* src = Be + (size_t)(n0 + i * 64 + arow) * K2 + k0 + acol;
            load_lds16(src, (char*)Bs + i * 4096 + wv * 1024);
        }
        __syncthreads();
        bh8 afr[FM], bfr[FN];
#pragma unroll
        for (int i = 0; i < FM; ++i)
            afr[i] = *(const bh8*)&As[(wr * FM * 16 + i * 16 + frow) * 32 + fk];
#pragma unroll
        for (int j = 0; j < FN; ++j)
            bfr[j] = *(const bh8*)&Bs[(wc * FN * 16 + j * 16 + frow) * 32 + fk];
#pragma unroll
        for (int i = 0; i < FM; ++i)
#pragma unroll
            for (int j = 0; j < FN; ++j)
                acc[i][j] = __builtin_amdgcn_mfma_f32_16x16x32_bf16(
                    afr[i], bfr[j], acc[i][j], 0, 0, 0);
        __syncthreads();
    }

    const int col = lane & 15;
    const int rbase = (lane >> 4) * 4;
#pragma unroll
    for (int i = 0; i < FM; ++i) {
#pragma unroll
        for (int r = 0; r < 4; ++r) {
            const int m = m0 + wr * FM * 16 + i * 16 + rbase + r;
#pragma unroll
            for (int j = 0; j < FN; ++j) {
                const int n = n0 + wc * FN * 16 + j * 16 + col;
                C[(size_t)m * N + n] = acc[i][j][r] + bias[n];
            }
        }
    }
}

// ---------------------------------------------------------------------------
// Kernel 3a: Q/K conversion for MFMA attention.
// Qe[bh][s][192] = [q_hi|q_hi|q_lo] of q*0.125 ;  Ke = [k_hi|k_lo|k_hi].
// ---------------------------------------------------------------------------
__global__ __launch_bounds__(256) void k_qk_convert(
    const float* __restrict__ qkv, unsigned short* __restrict__ Qe,
    unsigned short* __restrict__ Ke)
{
    const int gid = blockIdx.x * 256 + threadIdx.x;   // NBH*512*16
    const int d4 = gid & 15;
    const int s = (gid >> 4) & 511;
    const int bh = gid >> 13;
    const int b = bh / NH, h = bh - b * NH;
    const size_t t = (size_t)b * SEQ + s;
    const float4 q = ((const float4*)(qkv + t * D3 + h * HD))[d4];
    const float4 k = ((const float4*)(qkv + t * D3 + D + h * HD))[d4];
    ushort4 qh, ql, kh, kl;
    float4 qs = make_float4(q.x * 0.125f, q.y * 0.125f, q.z * 0.125f, q.w * 0.125f);
    qh.x = f2bf_rne(qs.x); qh.y = f2bf_rne(qs.y);
    qh.z = f2bf_rne(qs.z); qh.w = f2bf_rne(qs.w);
    ql.x = f2bf_rne(qs.x - bf2f(qh.x)); ql.y = f2bf_rne(qs.y - bf2f(qh.y));
    ql.z = f2bf_rne(qs.z - bf2f(qh.z)); ql.w = f2bf_rne(qs.w - bf2f(qh.w));
    kh.x = f2bf_rne(k.x); kh.y = f2bf_rne(k.y);
    kh.z = f2bf_rne(k.z); kh.w = f2bf_rne(k.w);
    kl.x = f2bf_rne(k.x - bf2f(kh.x)); kl.y = f2bf_rne(k.y - bf2f(kh.y));
    kl.z = f2bf_rne(k.z - bf2f(kh.z)); kl.w = f2bf_rne(k.w - bf2f(kh.w));
    ushort4* qrow = (ushort4*)(Qe + ((size_t)bh * SEQ + s) * EK);
    qrow[d4] = qh; qrow[16 + d4] = qh; qrow[32 + d4] = ql;
    ushort4* krow = (ushort4*)(Ke + ((size_t)bh * SEQ + s) * EK);
    krow[d4] = kh; krow[16 + d4] = kl; krow[32 + d4] = kh;
}

// ---------------------------------------------------------------------------
// Kernel 3b: V transpose to Vt[bh][d=64][s=512] bf16 (LDS transpose).
// ---------------------------------------------------------------------------
__global__ __launch_bounds__(256) void k_v_transpose(
    const float* __restrict__ qkv, unsigned short* __restrict__ Vt)
{
    __shared__ unsigned short T[64 * 72];
    const int bid = blockIdx.x;
    const int sb = bid & 7;
    const int bh = bid >> 3;
    const int b = bh / NH, h = bh - b * NH;
    const int tid = threadIdx.x;
    const int s0 = sb * 64;
    {
        const int ss = tid >> 2, cq = tid & 3;
        const float* src = qkv + ((size_t)(b * SEQ + s0 + ss)) * D3 + 2 * D + h * HD;
#pragma unroll
        for (int i = 0; i < 4; ++i) {
            float4 v = ((const float4*)src)[cq * 4 + i];
            ushort4 u;
            u.x = f2bf_rne(v.x); u.y = f2bf_rne(v.y);
            u.z = f2bf_rne(v.z); u.w = f2bf_rne(v.w);
            *(ushort4*)&T[ss * 72 + (cq * 4 + i) * 4] = u;
        }
    }
    __syncthreads();
    {
        const int d = tid >> 2, cs = tid & 3;
        __align__(16) unsigned short tmp[16];
#pragma unroll
        for (int j = 0; j < 16; ++j)
            tmp[j] = T[(cs * 16 + j) * 72 + d];
        unsigned short* dst = Vt + ((size_t)bh * HD + d) * SEQ + s0 + cs * 16;
        *(bh8*)dst = *(const bh8*)tmp;
        *(bh8*)(dst + 8) = *(const bh8*)(tmp + 8);
    }
}

// ---------------------------------------------------------------------------
// Kernel 3c: MFMA flash attention. 4 waves per (bh, 64-row Q-block).
// ---------------------------------------------------------------------------
__global__ __launch_bounds__(256) void k_attn_mfma(
    const unsigned short* __restrict__ Qe, const unsigned short* __restrict__ Ke,
    const unsigned short* __restrict__ Vt, float* __restrict__ attn)
{
    __shared__ __align__(16) unsigned short Ks[64 * 200];
    __shared__ __align__(16) unsigned short Vs[64 * 72];
    __shared__ __align__(16) unsigned short Ps[4 * 16 * 72];

    const int bid = blockIdx.x;
    const int qb = bid & 7;
    const int bh = bid >> 3;
    const int b = bh / NH, h = bh - b * NH;
    const int tid = threadIdx.x;
    const int lane = tid & 63;
    const int wv = tid >> 6;
    const int lg = lane >> 4;
    const int lr = lane & 15;
    const int q0 = qb * 64 + wv * 16;

    bh8 qa[6];
    {
        const unsigned short* qrow = Qe + ((size_t)bh * SEQ + q0 + lr) * EK + lg * 8;
#pragma unroll
        for (int kc = 0; kc < 6; ++kc)
            qa[kc] = *(const bh8*)(qrow + kc * 32);
    }

    fx4 o[4] = {};
    float m4[4], l4[4];
#pragma unroll
    for (int r = 0; r < 4; ++r) { m4[r] = -INFINITY; l4[r] = 0.f; }

    const int sr = tid >> 2, sc = tid & 3;
    bh8 kreg[6], vreg[2];
    {
        const unsigned short* ksrc = Ke + ((size_t)bh * SEQ + sr) * EK + sc * 48;
#pragma unroll
        for (int j = 0; j < 6; ++j) kreg[j] = *(const bh8*)(ksrc + j * 8);
        const unsigned short* vsrc = Vt + ((size_t)bh * HD + sr) * SEQ + sc * 16;
#pragma unroll
        for (int j = 0; j < 2; ++j) vreg[j] = *(const bh8*)(vsrc + j * 8);
    }

    for (int kt = 0; kt < 8; ++kt) {
        __syncthreads();
#pragma unroll
        for (int j = 0; j < 6; ++j)
            *(bh8*)&Ks[sr * 200 + sc * 48 + j * 8] = kreg[j];
#pragma unroll
        for (int j = 0; j < 2; ++j)
            *(bh8*)&Vs[sr * 72 + sc * 16 + j * 8] = vreg[j];
        __syncthreads();
        if (kt < 7) {
            const int kv1 = (kt + 1) * 64;
            const unsigned short* ksrc = Ke + ((size_t)bh * SEQ + kv1 + sr) * EK + sc * 48;
#pragma unroll
            for (int j = 0; j < 6; ++j) kreg[j] = *(const bh8*)(ksrc + j * 8);
            const unsigned short* vsrc = Vt + ((size_t)bh * HD + sr) * SEQ + kv1 + sc * 16;
#pragma unroll
            for (int j = 0; j < 2; ++j) vreg[j] = *(const bh8*)(vsrc + j * 8);
        }

        fx4 sf[4] = {};
#pragma unroll
        for (int kc = 0; kc < 6; ++kc) {
            bh8 kb[4];
#pragma unroll
            for (int j = 0; j < 4; ++j)
                kb[j] = *(const bh8*)&Ks[(j * 16 + lr) * 200 + kc * 32 + lg * 8];
#pragma unroll
            for (int j = 0; j < 4; ++j)
                sf[j] = __builtin_amdgcn_mfma_f32_16x16x32_bf16(qa[kc], kb[j], sf[j], 0, 0, 0);
        }

        float mxr[4];
#pragma unroll
        for (int r = 0; r < 4; ++r)
            mxr[r] = fmaxf(fmaxf(sf[0][r], sf[1][r]), fmaxf(sf[2][r], sf[3][r]));
#pragma unroll
        for (int off = 1; off < 16; off <<= 1)
#pragma unroll
            for (int r = 0; r < 4; ++r)
                mxr[r] = fmaxf(mxr[r], __shfl_xor(mxr[r], off));
        float corr[4];
#pragma unroll
        for (int r = 0; r < 4; ++r) {
            const float mn = fmaxf(m4[r], mxr[r]);
            corr[r] = expf(m4[r] - mn);
            m4[r] = mn;
        }
#pragma unroll
        for (int j = 0; j < 4; ++j)
#pragma unroll
            for (int r = 0; r < 4; ++r)
                sf[j][r] = expf(sf[j][r] - m4[r]);
        float rs[4];
#pragma unroll
        for (int r = 0; r < 4; ++r)
            rs[r] = (sf[0][r] + sf[1][r]) + (sf[2][r] + sf[3][r]);
#pragma unroll
        for (int off = 1; off < 16; off <<= 1)
#pragma unroll
            for (int r = 0; r < 4; ++r)
                rs[r] += __shfl_xor(rs[r], off);
#pragma unroll
        for (int r = 0; r < 4; ++r)
            l4[r] = l4[r] * corr[r] + rs[r];
#pragma unroll
        for (int j = 0; j < 4; ++j)
#pragma unroll
            for (int r = 0; r < 4; ++r)
                o[j][r] *= corr[r];

        unsigned short* pw = Ps + wv * (16 * 72);
#pragma unroll
        for (int j = 0; j < 4; ++j)
#pragma unroll
            for (int r = 0; r < 4; ++r)
                pw[(lg * 4 + r) * 72 + j * 16 + lr] = f2bf_rne(sf[j][r]);

#pragma unroll
        for (int kc = 0; kc < 2; ++kc) {
            bh8 pa = *(const bh8*)&pw[lr * 72 + kc * 32 + lg * 8];
            bh8 vb[4];
#pragma unroll
            for (int j = 0; j < 4; ++j)
                vb[j] = *(const bh8*)&Vs[(j * 16 + lr) * 72 + kc * 32 + lg * 8];
#pragma unroll
            for (int j = 0; j < 4; ++j)
                o[j] = __builtin_amdgcn_mfma_f32_16x16x32_bf16(pa, vb[j], o[j], 0, 0, 0);
        }
    }

    float inv[4];
#pragma unroll
    for (int r = 0; r < 4; ++r) inv[r] = 1.f / l4[r];
    const int srow = b * SEQ + q0 + lg * 4;
#pragma unroll
    for (int j = 0; j < 4; ++j)
#pragma unroll
        for (int r = 0; r < 4; ++r)
            attn[(size_t)(srow + r) * D + h * HD + j * 16 + lr] = o[j][r] * inv[r];
}

// ---------------------------------------------------------------------------
extern "C" void kernel_launch(void* const* d_in, const int* in_sizes, int n_in,
                              void* d_out, int out_size, void* d_ws, size_t ws_size,
                              hipStream_t stream)
{
    const float* x      = (const float*)d_in[0];
    const float* W_qkv  = (const float*)d_in[1];
    const float* b_qkv  = (const float*)d_in[2];
    const float* W_gate = (const float*)d_in[3];
    const float* b_gate = (const float*)d_in[4];
    const float* A      = (const float*)d_in[5];
    const float* B_lora = (const float*)d_in[6];
    const float* W_proj = (const float*)d_in[7];
    const float* b_proj = (const float*)d_in[8];
    float* out = (float*)d_out;

    // workspace layout (~95 MB); regB time-shared across phases
    float* qkv  = (float*)d_ws;                        // TT*D3
    float* attn = qkv + (size_t)TT * D3;               // TT*D
    float* regB = attn + (size_t)TT * D;

    // phase A: K-extended operands for QKV GEMM (incl. LoRA tail)
    unsigned short* A2 = (unsigned short*)regB;        // TT x KQ
    unsigned short* B2 = A2 + (size_t)TT * KQ;         // D3 x KQ
    // phase B: attention operands
    unsigned short* Qe = (unsigned short*)regB;        // NBH x 512 x 192
    unsigned short* Ke = Qe + (size_t)NBH * SEQ * EK;
    unsigned short* Vt = Ke + (size_t)NBH * SEQ * EK;  // NBH x 64 x 512
    // phase C: proj operands
    unsigned short* Ae2 = (unsigned short*)regB;       // TT x KE
    unsigned short* Wpe = Ae2 + (size_t)TT * KE;       // D x KE

    // 1. conversions + router/LoRA-down (router fills A2's 256-col tail)
    k_convert<KQ, true ><<<(TT * 192 + 255) / 256, 256, 0, stream>>>(x, A2, TT);
    k_convert<KQ, false><<<(D3 * 192 + 255) / 256, 256, 0, stream>>>(W_qkv, B2, D3);
    k_blora<<<(D3 * 128 + 255) / 256, 256, 0, stream>>>(B_lora, B2);
    k_router<<<TT, 64, 0, stream>>>(x, W_gate, b_gate, A, A2);

    // 2. QKV GEMM (bf16x3 + folded LoRA, K=2560) + bias
    {
        dim3 grid(D3 / 128, TT / 128);
        k_gemm_mfma<4, 4><<<grid, 256, 0, stream>>>(A2, B2, b_qkv, qkv, D3, KQ);
    }

    // 3. attention
    k_qk_convert<<<NBH * SEQ * 16 / 256, 256, 0, stream>>>(qkv, Qe, Ke);
    k_v_transpose<<<NBH * 8, 256, 0, stream>>>(qkv, Vt);
    k_attn_mfma<<<NBH * 8, 256, 0, stream>>>(Qe, Ke, Vt, attn);

    // 4. output projection (bf16x3 MFMA)
    k_convert<KE, true ><<<(TT * 192 + 255) / 256, 256, 0, stream>>>(attn, Ae2, TT);
    k_convert<KE, false><<<(D * 192 + 255) / 256, 256, 0, stream>>>(W_proj, Wpe, D);
    {
        dim3 grid(D / 128, TT / 64);
        k_gemm_mfma<2, 4><<<grid, 256, 0, stream>>>(Ae2, Wpe, b_proj, out, D, KE);
    }
}

// Round 6
// 208.210 us; speedup vs baseline: 6.7759x; 1.0875x over previous
//
#include <hip/hip_runtime.h>
#include <hip/hip_bf16.h>

// Problem constants
#define B_SZ 8
#define SEQ 512
#define D 768
#define D3 2304
#define NH 12
#define HD 64
#define NE 8
#define RANK 16
#define TT (B_SZ * SEQ)           // 4096 tokens
#define SCALING 2.0f              // ALPHA / RANK = 32/16
#define KE 2304                   // 3 * 768 (bf16x3 split)
#define KQ 2560                   // 2304 + 2*128 (LoRA-up folded into K)
#define EK 192                    // extended head dim = 3 * 64
#define NBH (B_SZ * NH)           // 96

typedef __attribute__((ext_vector_type(8))) short bh8;
typedef __attribute__((ext_vector_type(4))) float fx4;

__device__ __forceinline__ unsigned short f2bf_rne(float x) {
    unsigned u = __float_as_uint(x);
    unsigned r = (u + 0x7FFFu + ((u >> 16) & 1u)) >> 16;
    return (unsigned short)r;
}
__device__ __forceinline__ float bf2f(unsigned short b) {
    return __uint_as_float(((unsigned)b) << 16);
}
__device__ __forceinline__ void load_lds16(const void* g, void* l) {
    __builtin_amdgcn_global_load_lds(
        (const __attribute__((address_space(1))) unsigned int*)g,
        (__attribute__((address_space(3))) unsigned int*)l,
        16, 0, 0);
}

// ---------------------------------------------------------------------------
// bf16x3 split conversion: in [M][768] fp32 -> first 2304 cols of out rows
// (row stride RS shorts). A-layout: [hi|hi|lo]; B-layout: [hi|lo|hi].
// ---------------------------------------------------------------------------
template <int RS, bool ALAY>
__global__ __launch_bounds__(256) void k_convert(
    const float* __restrict__ in, unsigned short* __restrict__ out, int M)
{
    const int gid = blockIdx.x * 256 + threadIdx.x;
    if (gid >= M * 192) return;
    const int r = gid / 192;
    const int c4 = gid - r * 192;
    const float4 v = ((const float4*)(in + (size_t)r * D))[c4];
    ushort4 hi, lo;
    hi.x = f2bf_rne(v.x); hi.y = f2bf_rne(v.y);
    hi.z = f2bf_rne(v.z); hi.w = f2bf_rne(v.w);
    lo.x = f2bf_rne(v.x - bf2f(hi.x)); lo.y = f2bf_rne(v.y - bf2f(hi.y));
    lo.z = f2bf_rne(v.z - bf2f(hi.z)); lo.w = f2bf_rne(v.w - bf2f(hi.w));
    ushort4* row = (ushort4*)(out + (size_t)r * RS);
    row[c4] = hi;
    row[c4 + 192] = ALAY ? hi : lo;
    row[c4 + 384] = ALAY ? lo : hi;
}

// ---------------------------------------------------------------------------
// B_lora tail fill: B2[n][2304+p] = B2[n][2432+p] = bf16(Bup[e][n][r])
// ---------------------------------------------------------------------------
__global__ __launch_bounds__(256) void k_blora(
    const float* __restrict__ Bup, unsigned short* __restrict__ B2)
{
    const int gid = blockIdx.x * 256 + threadIdx.x;
    if (gid >= D3 * 128) return;
    const int n = gid >> 7;
    const int p = gid & 127;
    const int e = p >> 4, r = p & 15;
    const unsigned short h = f2bf_rne(Bup[((size_t)e * D3 + n) * RANK + r]);
    B2[(size_t)n * KQ + 2304 + p] = h;
    B2[(size_t)n * KQ + 2432 + p] = h;
}

// ---------------------------------------------------------------------------
// Kernel 1: router (softmax gate, top-2) + LoRA down; writes the 256-entry
// bf16 tail [v_hi | v_lo] of A2 rows (weights + scaling folded).
// ---------------------------------------------------------------------------
__global__ __launch_bounds__(64) void k_router(
    const float* __restrict__ x, const float* __restrict__ Wg,
    const float* __restrict__ bg, const float* __restrict__ A,
    unsigned short* __restrict__ A2)
{
    const int t = blockIdx.x;
    const int l = threadIdx.x;
    const float* xr = x + (size_t)t * D;

    float xv[12];
#pragma unroll
    for (int i = 0; i < 12; ++i) xv[i] = xr[l + 64 * i];

    float p[NE];
#pragma unroll
    for (int e = 0; e < NE; ++e) {
        const float* w = Wg + (size_t)e * D;
        float s = 0.f;
#pragma unroll
        for (int i = 0; i < 12; ++i) s += xv[i] * w[l + 64 * i];
#pragma unroll
        for (int off = 32; off; off >>= 1) s += __shfl_xor(s, off);
        p[e] = s + bg[e];
    }
    float mx = p[0];
#pragma unroll
    for (int e = 1; e < NE; ++e) mx = fmaxf(mx, p[e]);
    float den = 0.f;
#pragma unroll
    for (int e = 0; e < NE; ++e) { p[e] = expf(p[e] - mx); den += p[e]; }
    int i0 = 0;
#pragma unroll
    for (int e = 1; e < NE; ++e) if (p[e] > p[i0]) i0 = e;
    int i1 = (i0 == 0) ? 1 : 0;
#pragma unroll
    for (int e = 0; e < NE; ++e) if (e != i1 && e != i0 && p[e] > p[i1]) i1 = e;
    const float w0 = p[i0] / den * SCALING;
    const float w1 = p[i1] / den * SCALING;

    unsigned short tv0 = 0, tv1 = 0, tv2 = 0, tv3 = 0;
    const int base = 4 * l;

#pragma unroll
    for (int j = 0; j < 2; ++j) {
        const int e = j ? i1 : i0;
        const float wj = j ? w1 : w0;
        const float* Ae = A + (size_t)e * RANK * D;
#pragma unroll
        for (int r = 0; r < RANK; ++r) {
            const float* a = Ae + (size_t)r * D;
            float s = 0.f;
#pragma unroll
            for (int i = 0; i < 12; ++i) s += xv[i] * a[l + 64 * i];
#pragma unroll
            for (int off = 32; off; off >>= 1) s += __shfl_xor(s, off);
            const float val = s * wj;
            const unsigned short hi = f2bf_rne(val);
            const unsigned short lo = f2bf_rne(val - bf2f(hi));
            const int ph = e * 16 + r;
            const int pl = ph + 128;
            tv0 = (base + 0 == ph) ? hi : ((base + 0 == pl) ? lo : tv0);
            tv1 = (base + 1 == ph) ? hi : ((base + 1 == pl) ? lo : tv1);
            tv2 = (base + 2 == ph) ? hi : ((base + 2 == pl) ? lo : tv2);
            tv3 = (base + 3 == ph) ? hi : ((base + 3 == pl) ? lo : tv3);
        }
    }
    ushort4 tq; tq.x = tv0; tq.y = tv1; tq.z = tv2; tq.w = tv3;
    *(ushort4*)(A2 + (size_t)t * KQ + 2304 + base) = tq;
}

// ---------------------------------------------------------------------------
// Kernel 2: bf16 MFMA GEMM (m97 structure) + bias, XCD-swizzled grid.
// EPI=0: write fp32 C. EPI=1: fused QKV epilogue -> Qe/Ke (bf16 hi/lo,
// Q scaled by 0.125) and transposed Vt, no fp32 output.
// ---------------------------------------------------------------------------
template <int FM, int FN, int EPI>
__global__ __launch_bounds__(256) void k_gemm_mfma(
    const unsigned short* __restrict__ Ae, const unsigned short* __restrict__ Be,
    const float* __restrict__ bias, float* __restrict__ C,
    int N, int K2,
    unsigned short* __restrict__ Qe, unsigned short* __restrict__ Ke,
    unsigned short* __restrict__ Vt)
{
    constexpr int BM = 2 * FM * 16;
    constexpr int BN = 2 * FN * 16;
    constexpr int ISS_A = BM / 64;
    constexpr int ISS_B = BN / 64;
    __shared__ __align__(16) unsigned short As[BM * 32];
    __shared__ __align__(16) unsigned short Bs[BN * 32];

    // XCD-aware bijective swizzle (grid count divisible by 8)
    const int nwg = gridDim.x * gridDim.y;
    const int id = blockIdx.y * gridDim.x + blockIdx.x;
    const int cpx = nwg >> 3;
    const int swz = (id & 7) * cpx + (id >> 3);
    const int gx = swz % gridDim.x;
    const int gy = swz / gridDim.x;

    const int tid = threadIdx.x;
    const int lane = tid & 63;
    const int wv = tid >> 6;
    const int wr = wv >> 1, wc = wv & 1;
    const int m0 = gy * BM;
    const int n0 = gx * BN;

    fx4 acc[FM][FN] = {};

    const int arow = wv * 16 + (lane >> 2);
    const int acol = (lane & 3) * 8;
    const int frow = lane & 15;
    const int fk = (lane >> 4) * 8;

    for (int k0 = 0; k0 < K2; k0 += 32) {
#pragma unroll
        for (int i = 0; i < ISS_A; ++i) {
            const unsigned short* src = Ae + (size_t)(m0 + i * 64 + arow) * K2 + k0 + acol;
            load_lds16(src, (char*)As + i * 4096 + wv * 1024);
        }
#pragma unroll
        for (int i = 0; i < ISS_B; ++i) {
            const unsigned short* src = Be + (size_t)(n0 + i * 64 + arow) * K2 + k0 + acol;
            load_lds16(src, (char*)Bs + i * 4096 + wv * 1024);
        }
        __syncthreads();
        bh8 afr[FM], bfr[FN];
#pragma unroll
        for (int i = 0; i < FM; ++i)
            afr[i] = *(const bh8*)&As[(wr * FM * 16 + i * 16 + frow) * 32 + fk];
#pragma unroll
        for (int j = 0; j < FN; ++j)
            bfr[j] = *(const bh8*)&Bs[(wc * FN * 16 + j * 16 + frow) * 32 + fk];
#pragma unroll
        for (int i = 0; i < FM; ++i)
#pragma unroll
            for (int j = 0; j < FN; ++j)
                acc[i][j] = __builtin_amdgcn_mfma_f32_16x16x32_bf16(
                    afr[i], bfr[j], acc[i][j], 0, 0, 0);
        __syncthreads();
    }

    const int col = lane & 15;
    const int rbase = (lane >> 4) * 4;

    if (EPI == 0) {
#pragma unroll
        for (int i = 0; i < FM; ++i) {
#pragma unroll
            for (int r = 0; r < 4; ++r) {
                const int m = m0 + wr * FM * 16 + i * 16 + rbase + r;
#pragma unroll
                for (int j = 0; j < FN; ++j) {
                    const int n = n0 + wc * FN * 16 + j * 16 + col;
                    C[(size_t)m * N + n] = acc[i][j][r] + bias[n];
                }
            }
        }
    } else {
        const int sec = n0 / D;   // 0=Q, 1=K, 2=V (block-uniform: tiles 128-aligned)
#pragma unroll
        for (int i = 0; i < FM; ++i) {
            const int mb = m0 + wr * FM * 16 + i * 16 + rbase;
#pragma unroll
            for (int j = 0; j < FN; ++j) {
                const int n = n0 + wc * FN * 16 + j * 16 + col;
                const int n2 = n - sec * D;
                const int h = n2 >> 6, d0 = n2 & 63;
                const float bi = bias[n];
                if (sec == 2) {
                    // V: transposed bf16 write, vectorized along m
                    ushort4 vq;
                    vq.x = f2bf_rne(acc[i][j][0] + bi);
                    vq.y = f2bf_rne(acc[i][j][1] + bi);
                    vq.z = f2bf_rne(acc[i][j][2] + bi);
                    vq.w = f2bf_rne(acc[i][j][3] + bi);
                    const int b = mb >> 9, s = mb & 511;
                    *(ushort4*)(Vt + ((size_t)(b * NH + h) * HD + d0) * SEQ + s) = vq;
                } else {
#pragma unroll
                    for (int r = 0; r < 4; ++r) {
                        const int m = mb + r;
                        const int b = m >> 9, s = m & 511;
                        float c = acc[i][j][r] + bi;
                        if (sec == 0) c *= 0.125f;
                        const unsigned short hi = f2bf_rne(c);
                        const unsigned short lo = f2bf_rne(c - bf2f(hi));
                        unsigned short* row =
                            (sec == 0 ? Qe : Ke) + ((size_t)(b * NH + h) * SEQ + s) * EK;
                        if (sec == 0) {        // Q: [hi | hi | lo]
                            row[d0] = hi; row[64 + d0] = hi; row[128 + d0] = lo;
                        } else {               // K: [hi | lo | hi]
                            row[d0] = hi; row[64 + d0] = lo; row[128 + d0] = hi;
                        }
                    }
                }
            }
        }
    }
}

// ---------------------------------------------------------------------------
// Kernel 3: MFMA flash attention. 4 waves per (bh, 64-row Q-block).
// Epilogue writes Ae2 (proj A-operand) directly in bf16x3 [hi|hi|lo] layout.
// ---------------------------------------------------------------------------
__global__ __launch_bounds__(256) void k_attn_mfma(
    const unsigned short* __restrict__ Qe, const unsigned short* __restrict__ Ke,
    const unsigned short* __restrict__ Vt, unsigned short* __restrict__ Ae2)
{
    __shared__ __align__(16) unsigned short Ks[64 * 200];
    __shared__ __align__(16) unsigned short Vs[64 * 72];
    __shared__ __align__(16) unsigned short Ps[4 * 16 * 72];

    const int bid = blockIdx.x;
    const int qb = bid & 7;
    const int bh = bid >> 3;
    const int b = bh / NH, h = bh - b * NH;
    const int tid = threadIdx.x;
    const int lane = tid & 63;
    const int wv = tid >> 6;
    const int lg = lane >> 4;
    const int lr = lane & 15;
    const int q0 = qb * 64 + wv * 16;

    bh8 qa[6];
    {
        const unsigned short* qrow = Qe + ((size_t)bh * SEQ + q0 + lr) * EK + lg * 8;
#pragma unroll
        for (int kc = 0; kc < 6; ++kc)
            qa[kc] = *(const bh8*)(qrow + kc * 32);
    }

    fx4 o[4] = {};
    float m4[4], l4[4];
#pragma unroll
    for (int r = 0; r < 4; ++r) { m4[r] = -INFINITY; l4[r] = 0.f; }

    const int sr = tid >> 2, sc = tid & 3;
    bh8 kreg[6], vreg[2];
    {
        const unsigned short* ksrc = Ke + ((size_t)bh * SEQ + sr) * EK + sc * 48;
#pragma unroll
        for (int j = 0; j < 6; ++j) kreg[j] = *(const bh8*)(ksrc + j * 8);
        const unsigned short* vsrc = Vt + ((size_t)bh * HD + sr) * SEQ + sc * 16;
#pragma unroll
        for (int j = 0; j < 2; ++j) vreg[j] = *(const bh8*)(vsrc + j * 8);
    }

    for (int kt = 0; kt < 8; ++kt) {
        __syncthreads();
#pragma unroll
        for (int j = 0; j < 6; ++j)
            *(bh8*)&Ks[sr * 200 + sc * 48 + j * 8] = kreg[j];
#pragma unroll
        for (int j = 0; j < 2; ++j)
            *(bh8*)&Vs[sr * 72 + sc * 16 + j * 8] = vreg[j];
        __syncthreads();
        if (kt < 7) {
            const int kv1 = (kt + 1) * 64;
            const unsigned short* ksrc = Ke + ((size_t)bh * SEQ + kv1 + sr) * EK + sc * 48;
#pragma unroll
            for (int j = 0; j < 6; ++j) kreg[j] = *(const bh8*)(ksrc + j * 8);
            const unsigned short* vsrc = Vt + ((size_t)bh * HD + sr) * SEQ + kv1 + sc * 16;
#pragma unroll
            for (int j = 0; j < 2; ++j) vreg[j] = *(const bh8*)(vsrc + j * 8);
        }

        fx4 sf[4] = {};
        __builtin_amdgcn_s_setprio(1);
#pragma unroll
        for (int kc = 0; kc < 6; ++kc) {
            bh8 kb[4];
#pragma unroll
            for (int j = 0; j < 4; ++j)
                kb[j] = *(const bh8*)&Ks[(j * 16 + lr) * 200 + kc * 32 + lg * 8];
#pragma unroll
            for (int j = 0; j < 4; ++j)
                sf[j] = __builtin_amdgcn_mfma_f32_16x16x32_bf16(qa[kc], kb[j], sf[j], 0, 0, 0);
        }
        __builtin_amdgcn_s_setprio(0);

        float mxr[4];
#pragma unroll
        for (int r = 0; r < 4; ++r)
            mxr[r] = fmaxf(fmaxf(sf[0][r], sf[1][r]), fmaxf(sf[2][r], sf[3][r]));
#pragma unroll
        for (int off = 1; off < 16; off <<= 1)
#pragma unroll
            for (int r = 0; r < 4; ++r)
                mxr[r] = fmaxf(mxr[r], __shfl_xor(mxr[r], off));
        float corr[4];
#pragma unroll
        for (int r = 0; r < 4; ++r) {
            const float mn = fmaxf(m4[r], mxr[r]);
            corr[r] = expf(m4[r] - mn);
            m4[r] = mn;
        }
#pragma unroll
        for (int j = 0; j < 4; ++j)
#pragma unroll
            for (int r = 0; r < 4; ++r)
                sf[j][r] = expf(sf[j][r] - m4[r]);
        float rs[4];
#pragma unroll
        for (int r = 0; r < 4; ++r)
            rs[r] = (sf[0][r] + sf[1][r]) + (sf[2][r] + sf[3][r]);
#pragma unroll
        for (int off = 1; off < 16; off <<= 1)
#pragma unroll
            for (int r = 0; r < 4; ++r)
                rs[r] += __shfl_xor(rs[r], off);
#pragma unroll
        for (int r = 0; r < 4; ++r)
            l4[r] = l4[r] * corr[r] + rs[r];
#pragma unroll
        for (int j = 0; j < 4; ++j)
#pragma unroll
            for (int r = 0; r < 4; ++r)
                o[j][r] *= corr[r];

        unsigned short* pw = Ps + wv * (16 * 72);
#pragma unroll
        for (int j = 0; j < 4; ++j)
#pragma unroll
            for (int r = 0; r < 4; ++r)
                pw[(lg * 4 + r) * 72 + j * 16 + lr] = f2bf_rne(sf[j][r]);

        __builtin_amdgcn_s_setprio(1);
#pragma unroll
        for (int kc = 0; kc < 2; ++kc) {
            bh8 pa = *(const bh8*)&pw[lr * 72 + kc * 32 + lg * 8];
            bh8 vb[4];
#pragma unroll
            for (int j = 0; j < 4; ++j)
                vb[j] = *(const bh8*)&Vs[(j * 16 + lr) * 72 + kc * 32 + lg * 8];
#pragma unroll
            for (int j = 0; j < 4; ++j)
                o[j] = __builtin_amdgcn_mfma_f32_16x16x32_bf16(pa, vb[j], o[j], 0, 0, 0);
        }
        __builtin_amdgcn_s_setprio(0);
    }

    float inv[4];
#pragma unroll
    for (int r = 0; r < 4; ++r) inv[r] = 1.f / l4[r];
    const int trow = b * SEQ + q0 + lg * 4;
#pragma unroll
    for (int r = 0; r < 4; ++r) {
        unsigned short* row = Ae2 + (size_t)(trow + r) * KE;
#pragma unroll
        for (int j = 0; j < 4; ++j) {
            const float v = o[j][r] * inv[r];
            const unsigned short hi = f2bf_rne(v);
            const unsigned short lo = f2bf_rne(v - bf2f(hi));
            const int c = h * HD + j * 16 + lr;
            row[c] = hi; row[768 + c] = hi; row[1536 + c] = lo;
        }
    }
}

// ---------------------------------------------------------------------------
extern "C" void kernel_launch(void* const* d_in, const int* in_sizes, int n_in,
                              void* d_out, int out_size, void* d_ws, size_t ws_size,
                              hipStream_t stream)
{
    const float* x      = (const float*)d_in[0];
    const float* W_qkv  = (const float*)d_in[1];
    const float* b_qkv  = (const float*)d_in[2];
    const float* W_gate = (const float*)d_in[3];
    const float* b_gate = (const float*)d_in[4];
    const float* A      = (const float*)d_in[5];
    const float* B_lora = (const float*)d_in[6];
    const float* W_proj = (const float*)d_in[7];
    const float* b_proj = (const float*)d_in[8];
    float* out = (float*)d_out;

    // workspace layout (shorts), ~80 MB total. Ae2 aliases A2 (disjoint lifetimes).
    unsigned short* A2  = (unsigned short*)d_ws;       // TT x KQ   (dead after QKV GEMM)
    unsigned short* B2  = A2 + (size_t)TT * KQ;        // D3 x KQ
    unsigned short* Qe  = B2 + (size_t)D3 * KQ;        // NBH x 512 x 192
    unsigned short* Ke  = Qe + (size_t)NBH * SEQ * EK; // NBH x 512 x 192
    unsigned short* Vt  = Ke + (size_t)NBH * SEQ * EK; // NBH x 64 x 512
    unsigned short* Wpe = Vt + (size_t)NBH * HD * SEQ; // D x KE
    unsigned short* Ae2 = A2;                          // TT x KE (written by attn)

    // 1. operand conversions + router/LoRA-down (router fills A2's 256-col tail)
    k_convert<KQ, true ><<<(TT * 192 + 255) / 256, 256, 0, stream>>>(x, A2, TT);
    k_convert<KQ, false><<<(D3 * 192 + 255) / 256, 256, 0, stream>>>(W_qkv, B2, D3);
    k_blora<<<(D3 * 128 + 255) / 256, 256, 0, stream>>>(B_lora, B2);
    k_router<<<TT, 64, 0, stream>>>(x, W_gate, b_gate, A, A2);
    k_convert<KE, false><<<(D * 192 + 255) / 256, 256, 0, stream>>>(W_proj, Wpe, D);

    // 2. QKV GEMM (bf16x3 + folded LoRA, K=2560) + fused Q/K/V-format epilogue
    {
        dim3 grid(D3 / 128, TT / 128);
        k_gemm_mfma<4, 4, 1><<<grid, 256, 0, stream>>>(
            A2, B2, b_qkv, nullptr, D3, KQ, Qe, Ke, Vt);
    }

    // 3. MFMA flash attention -> Ae2 (bf16x3, proj-ready)
    k_attn_mfma<<<NBH * 8, 256, 0, stream>>>(Qe, Ke, Vt, Ae2);

    // 4. output projection (bf16x3 MFMA)
    {
        dim3 grid(D / 128, TT / 64);
        k_gemm_mfma<2, 4, 0><<<grid, 256, 0, stream>>>(
            Ae2, Wpe, b_proj, out, D, KE, nullptr, nullptr, nullptr);
    }
}

// Round 7
// 173.530 us; speedup vs baseline: 8.1300x; 1.1999x over previous
//
#include <hip/hip_runtime.h>
#include <hip/hip_bf16.h>

// Problem constants
#define B_SZ 8
#define SEQ 512
#define D 768
#define D3 2304
#define NH 12
#define HD 64
#define NE 8
#define RANK 16
#define TT (B_SZ * SEQ)           // 4096 tokens
#define SCALING 2.0f              // ALPHA / RANK = 32/16
#define KE 2304                   // 3 * 768 (bf16x3 split)
#define KQ 2560                   // 2304 + 2*128 (LoRA-up folded into K)
#define EK 192                    // extended head dim = 3 * 64
#define NBH (B_SZ * NH)           // 96

typedef __attribute__((ext_vector_type(8))) short bh8;
typedef __attribute__((ext_vector_type(4))) float fx4;

__device__ __forceinline__ unsigned short f2bf_rne(float x) {
    unsigned u = __float_as_uint(x);
    unsigned r = (u + 0x7FFFu + ((u >> 16) & 1u)) >> 16;
    return (unsigned short)r;
}
__device__ __forceinline__ float bf2f(unsigned short b) {
    return __uint_as_float(((unsigned)b) << 16);
}
__device__ __forceinline__ void load_lds16(const void* g, void* l) {
    __builtin_amdgcn_global_load_lds(
        (const __attribute__((address_space(1))) unsigned int*)g,
        (__attribute__((address_space(3))) unsigned int*)l,
        16, 0, 0);
}

// ---------------------------------------------------------------------------
// bf16x3 split conversion: in [M][768] fp32 -> first 2304 cols of out rows
// (row stride RS shorts). A-layout: [hi|hi|lo]; B-layout: [hi|lo|hi].
// ---------------------------------------------------------------------------
template <int RS, bool ALAY>
__global__ __launch_bounds__(256) void k_convert(
    const float* __restrict__ in, unsigned short* __restrict__ out, int M)
{
    const int gid = blockIdx.x * 256 + threadIdx.x;
    if (gid >= M * 192) return;
    const int r = gid / 192;
    const int c4 = gid - r * 192;
    const float4 v = ((const float4*)(in + (size_t)r * D))[c4];
    ushort4 hi, lo;
    hi.x = f2bf_rne(v.x); hi.y = f2bf_rne(v.y);
    hi.z = f2bf_rne(v.z); hi.w = f2bf_rne(v.w);
    lo.x = f2bf_rne(v.x - bf2f(hi.x)); lo.y = f2bf_rne(v.y - bf2f(hi.y));
    lo.z = f2bf_rne(v.z - bf2f(hi.z)); lo.w = f2bf_rne(v.w - bf2f(hi.w));
    ushort4* row = (ushort4*)(out + (size_t)r * RS);
    row[c4] = hi;
    row[c4 + 192] = ALAY ? hi : lo;
    row[c4 + 384] = ALAY ? lo : hi;
}

// ---------------------------------------------------------------------------
// B_lora tail fill: B2[n][2304+p] = B2[n][2432+p] = bf16(Bup[e][n][r])
// ---------------------------------------------------------------------------
__global__ __launch_bounds__(256) void k_blora(
    const float* __restrict__ Bup, unsigned short* __restrict__ B2)
{
    const int gid = blockIdx.x * 256 + threadIdx.x;
    if (gid >= D3 * 128) return;
    const int n = gid >> 7;
    const int p = gid & 127;
    const int e = p >> 4, r = p & 15;
    const unsigned short h = f2bf_rne(Bup[((size_t)e * D3 + n) * RANK + r]);
    B2[(size_t)n * KQ + 2304 + p] = h;
    B2[(size_t)n * KQ + 2432 + p] = h;
}

// ---------------------------------------------------------------------------
// Kernel 1: router (softmax gate, top-2) + LoRA down; writes the 256-entry
// bf16 tail [v_hi | v_lo] of A2 rows (weights + scaling folded).
// ---------------------------------------------------------------------------
__global__ __launch_bounds__(64) void k_router(
    const float* __restrict__ x, const float* __restrict__ Wg,
    const float* __restrict__ bg, const float* __restrict__ A,
    unsigned short* __restrict__ A2)
{
    const int t = blockIdx.x;
    const int l = threadIdx.x;
    const float* xr = x + (size_t)t * D;

    float xv[12];
#pragma unroll
    for (int i = 0; i < 12; ++i) xv[i] = xr[l + 64 * i];

    float p[NE];
#pragma unroll
    for (int e = 0; e < NE; ++e) {
        const float* w = Wg + (size_t)e * D;
        float s = 0.f;
#pragma unroll
        for (int i = 0; i < 12; ++i) s += xv[i] * w[l + 64 * i];
#pragma unroll
        for (int off = 32; off; off >>= 1) s += __shfl_xor(s, off);
        p[e] = s + bg[e];
    }
    float mx = p[0];
#pragma unroll
    for (int e = 1; e < NE; ++e) mx = fmaxf(mx, p[e]);
    float den = 0.f;
#pragma unroll
    for (int e = 0; e < NE; ++e) { p[e] = expf(p[e] - mx); den += p[e]; }
    int i0 = 0;
#pragma unroll
    for (int e = 1; e < NE; ++e) if (p[e] > p[i0]) i0 = e;
    int i1 = (i0 == 0) ? 1 : 0;
#pragma unroll
    for (int e = 0; e < NE; ++e) if (e != i1 && e != i0 && p[e] > p[i1]) i1 = e;
    const float w0 = p[i0] / den * SCALING;
    const float w1 = p[i1] / den * SCALING;

    unsigned short tv0 = 0, tv1 = 0, tv2 = 0, tv3 = 0;
    const int base = 4 * l;

#pragma unroll
    for (int j = 0; j < 2; ++j) {
        const int e = j ? i1 : i0;
        const float wj = j ? w1 : w0;
        const float* Ae = A + (size_t)e * RANK * D;
#pragma unroll
        for (int r = 0; r < RANK; ++r) {
            const float* a = Ae + (size_t)r * D;
            float s = 0.f;
#pragma unroll
            for (int i = 0; i < 12; ++i) s += xv[i] * a[l + 64 * i];
#pragma unroll
            for (int off = 32; off; off >>= 1) s += __shfl_xor(s, off);
            const float val = s * wj;
            const unsigned short hi = f2bf_rne(val);
            const unsigned short lo = f2bf_rne(val - bf2f(hi));
            const int ph = e * 16 + r;
            const int pl = ph + 128;
            tv0 = (base + 0 == ph) ? hi : ((base + 0 == pl) ? lo : tv0);
            tv1 = (base + 1 == ph) ? hi : ((base + 1 == pl) ? lo : tv1);
            tv2 = (base + 2 == ph) ? hi : ((base + 2 == pl) ? lo : tv2);
            tv3 = (base + 3 == ph) ? hi : ((base + 3 == pl) ? lo : tv3);
        }
    }
    ushort4 tq; tq.x = tv0; tq.y = tv1; tq.z = tv2; tq.w = tv3;
    *(ushort4*)(A2 + (size_t)t * KQ + 2304 + base) = tq;
}

// ---------------------------------------------------------------------------
// Kernel 2: bf16 MFMA GEMM. BK=64, XOR-swizzled LDS (rule #21: linear
// global_load_lds dest + inverse-swizzled per-lane SOURCE col + XOR on read).
// Grids sized for exact blocks/CU balance (BN=96). XCD-swizzled.
// EPI=0: fp32 C + bias. EPI=1: fused QKV epilogue -> Qe/Ke (bf16 hi/lo,
// Q scaled by 0.125) and transposed Vt.
// ---------------------------------------------------------------------------
template <int FM, int FN, int EPI>
__global__ __launch_bounds__(256) void k_gemm_mfma(
    const unsigned short* __restrict__ Ae, const unsigned short* __restrict__ Be,
    const float* __restrict__ bias, float* __restrict__ C,
    int N, int K2,
    unsigned short* __restrict__ Qe, unsigned short* __restrict__ Ke,
    unsigned short* __restrict__ Vt)
{
    constexpr int BM = 2 * FM * 16;
    constexpr int BN = 2 * FN * 16;
    constexpr int ISS_A = BM / 32;       // 32 rows (of 128 B) per issue
    constexpr int ISS_B = BN / 32;
    __shared__ __align__(16) unsigned short As[BM * 64];
    __shared__ __align__(16) unsigned short Bs[BN * 64];

    // XCD-aware bijective swizzle (grid counts divisible by 8)
    const int id = blockIdx.y * gridDim.x + blockIdx.x;
    const int cpx = (gridDim.x * gridDim.y) >> 3;
    const int swz = (id & 7) * cpx + (id >> 3);
    const int gx = swz % gridDim.x;
    const int gy = swz / gridDim.x;

    const int tid = threadIdx.x;
    const int lane = tid & 63;
    const int wv = tid >> 6;
    const int wr = wv >> 1, wc = wv & 1;
    const int m0 = gy * BM;
    const int n0 = gx * BN;

    fx4 acc[FM][FN] = {};

    // staging: each issue = 256 lanes x 16B = 32 rows of 128 B.
    // row = wv*8 + (lane>>3); source 16B-unit = (lane&7) ^ (row&7)  (involution)
    const int arow = wv * 8 + (lane >> 3);
    const int acol = (((lane & 7) ^ (lane >> 3)) << 3);
    const int frow = lane & 15;

    for (int k0 = 0; k0 < K2; k0 += 64) {
#pragma unroll
        for (int i = 0; i < ISS_A; ++i)
            load_lds16(Ae + (size_t)(m0 + i * 32 + arow) * K2 + k0 + acol,
                       (char*)As + i * 4096 + wv * 1024);
#pragma unroll
        for (int i = 0; i < ISS_B; ++i)
            load_lds16(Be + (size_t)(n0 + i * 32 + arow) * K2 + k0 + acol,
                       (char*)Bs + i * 4096 + wv * 1024);
        __syncthreads();
#pragma unroll
        for (int kk = 0; kk < 2; ++kk) {
            // logical 16B-unit (kk*4 + lane>>4) XOR row&7 ( = lane&7 for 16-mult tiles)
            const int un = ((((kk << 2) | (lane >> 4)) ^ (lane & 7)) << 3);
            bh8 afr[FM], bfr[FN];
#pragma unroll
            for (int i = 0; i < FM; ++i)
                afr[i] = *(const bh8*)&As[(wr * FM * 16 + i * 16 + frow) * 64 + un];
#pragma unroll
            for (int j = 0; j < FN; ++j)
                bfr[j] = *(const bh8*)&Bs[(wc * FN * 16 + j * 16 + frow) * 64 + un];
#pragma unroll
            for (int i = 0; i < FM; ++i)
#pragma unroll
                for (int j = 0; j < FN; ++j)
                    acc[i][j] = __builtin_amdgcn_mfma_f32_16x16x32_bf16(
                        afr[i], bfr[j], acc[i][j], 0, 0, 0);
        }
        __syncthreads();
    }

    const int col = lane & 15;
    const int rbase = (lane >> 4) * 4;

    if (EPI == 0) {
#pragma unroll
        for (int i = 0; i < FM; ++i) {
#pragma unroll
            for (int r = 0; r < 4; ++r) {
                const int m = m0 + wr * FM * 16 + i * 16 + rbase + r;
#pragma unroll
                for (int j = 0; j < FN; ++j) {
                    const int n = n0 + wc * FN * 16 + j * 16 + col;
                    C[(size_t)m * N + n] = acc[i][j][r] + bias[n];
                }
            }
        }
    } else {
        const int sec = n0 / D;   // 0=Q, 1=K, 2=V (768 % 96 == 0: no tile crosses)
#pragma unroll
        for (int i = 0; i < FM; ++i) {
            const int mb = m0 + wr * FM * 16 + i * 16 + rbase;
#pragma unroll
            for (int j = 0; j < FN; ++j) {
                const int n = n0 + wc * FN * 16 + j * 16 + col;
                const int n2 = n - sec * D;
                const int h = n2 >> 6, d0 = n2 & 63;
                const float bi = bias[n];
                if (sec == 2) {
                    ushort4 vq;
                    vq.x = f2bf_rne(acc[i][j][0] + bi);
                    vq.y = f2bf_rne(acc[i][j][1] + bi);
                    vq.z = f2bf_rne(acc[i][j][2] + bi);
                    vq.w = f2bf_rne(acc[i][j][3] + bi);
                    const int b = mb >> 9, s = mb & 511;
                    *(ushort4*)(Vt + ((size_t)(b * NH + h) * HD + d0) * SEQ + s) = vq;
                } else {
#pragma unroll
                    for (int r = 0; r < 4; ++r) {
                        const int m = mb + r;
                        const int b = m >> 9, s = m & 511;
                        float c = acc[i][j][r] + bi;
                        if (sec == 0) c *= 0.125f;
                        const unsigned short hi = f2bf_rne(c);
                        const unsigned short lo = f2bf_rne(c - bf2f(hi));
                        unsigned short* row =
                            (sec == 0 ? Qe : Ke) + ((size_t)(b * NH + h) * SEQ + s) * EK;
                        if (sec == 0) {        // Q: [hi | hi | lo]
                            row[d0] = hi; row[64 + d0] = hi; row[128 + d0] = lo;
                        } else {               // K: [hi | lo | hi]
                            row[d0] = hi; row[64 + d0] = lo; row[128 + d0] = hi;
                        }
                    }
                }
            }
        }
    }
}

// ---------------------------------------------------------------------------
// Kernel 3: MFMA flash attention. 4 waves per (bh, 64-row Q-block).
// Epilogue writes Ae2 (proj A-operand) directly in bf16x3 [hi|hi|lo] layout.
// ---------------------------------------------------------------------------
__global__ __launch_bounds__(256) void k_attn_mfma(
    const unsigned short* __restrict__ Qe, const unsigned short* __restrict__ Ke,
    const unsigned short* __restrict__ Vt, unsigned short* __restrict__ Ae2)
{
    __shared__ __align__(16) unsigned short Ks[64 * 200];
    __shared__ __align__(16) unsigned short Vs[64 * 72];
    __shared__ __align__(16) unsigned short Ps[4 * 16 * 72];

    const int bid = blockIdx.x;
    const int qb = bid & 7;
    const int bh = bid >> 3;
    const int b = bh / NH, h = bh - b * NH;
    const int tid = threadIdx.x;
    const int lane = tid & 63;
    const int wv = tid >> 6;
    const int lg = lane >> 4;
    const int lr = lane & 15;
    const int q0 = qb * 64 + wv * 16;

    bh8 qa[6];
    {
        const unsigned short* qrow = Qe + ((size_t)bh * SEQ + q0 + lr) * EK + lg * 8;
#pragma unroll
        for (int kc = 0; kc < 6; ++kc)
            qa[kc] = *(const bh8*)(qrow + kc * 32);
    }

    fx4 o[4] = {};
    float m4[4], l4[4];
#pragma unroll
    for (int r = 0; r < 4; ++r) { m4[r] = -INFINITY; l4[r] = 0.f; }

    const int sr = tid >> 2, sc = tid & 3;
    bh8 kreg[6], vreg[2];
    {
        const unsigned short* ksrc = Ke + ((size_t)bh * SEQ + sr) * EK + sc * 48;
#pragma unroll
        for (int j = 0; j < 6; ++j) kreg[j] = *(const bh8*)(ksrc + j * 8);
        const unsigned short* vsrc = Vt + ((size_t)bh * HD + sr) * SEQ + sc * 16;
#pragma unroll
        for (int j = 0; j < 2; ++j) vreg[j] = *(const bh8*)(vsrc + j * 8);
    }

    for (int kt = 0; kt < 8; ++kt) {
        __syncthreads();
#pragma unroll
        for (int j = 0; j < 6; ++j)
            *(bh8*)&Ks[sr * 200 + sc * 48 + j * 8] = kreg[j];
#pragma unroll
        for (int j = 0; j < 2; ++j)
            *(bh8*)&Vs[sr * 72 + sc * 16 + j * 8] = vreg[j];
        __syncthreads();
        if (kt < 7) {
            const int kv1 = (kt + 1) * 64;
            const unsigned short* ksrc = Ke + ((size_t)bh * SEQ + kv1 + sr) * EK + sc * 48;
#pragma unroll
            for (int j = 0; j < 6; ++j) kreg[j] = *(const bh8*)(ksrc + j * 8);
            const unsigned short* vsrc = Vt + ((size_t)bh * HD + sr) * SEQ + kv1 + sc * 16;
#pragma unroll
            for (int j = 0; j < 2; ++j) vreg[j] = *(const bh8*)(vsrc + j * 8);
        }

        fx4 sf[4] = {};
        __builtin_amdgcn_s_setprio(1);
#pragma unroll
        for (int kc = 0; kc < 6; ++kc) {
            bh8 kb[4];
#pragma unroll
            for (int j = 0; j < 4; ++j)
                kb[j] = *(const bh8*)&Ks[(j * 16 + lr) * 200 + kc * 32 + lg * 8];
#pragma unroll
            for (int j = 0; j < 4; ++j)
                sf[j] = __builtin_amdgcn_mfma_f32_16x16x32_bf16(qa[kc], kb[j], sf[j], 0, 0, 0);
        }
        __builtin_amdgcn_s_setprio(0);

        float mxr[4];
#pragma unroll
        for (int r = 0; r < 4; ++r)
            mxr[r] = fmaxf(fmaxf(sf[0][r], sf[1][r]), fmaxf(sf[2][r], sf[3][r]));
#pragma unroll
        for (int off = 1; off < 16; off <<= 1)
#pragma unroll
            for (int r = 0; r < 4; ++r)
                mxr[r] = fmaxf(mxr[r], __shfl_xor(mxr[r], off));
        float corr[4];
#pragma unroll
        for (int r = 0; r < 4; ++r) {
            const float mn = fmaxf(m4[r], mxr[r]);
            corr[r] = expf(m4[r] - mn);
            m4[r] = mn;
        }
#pragma unroll
        for (int j = 0; j < 4; ++j)
#pragma unroll
            for (int r = 0; r < 4; ++r)
                sf[j][r] = expf(sf[j][r] - m4[r]);
        float rs[4];
#pragma unroll
        for (int r = 0; r < 4; ++r)
            rs[r] = (sf[0][r] + sf[1][r]) + (sf[2][r] + sf[3][r]);
#pragma unroll
        for (int off = 1; off < 16; off <<= 1)
#pragma unroll
            for (int r = 0; r < 4; ++r)
                rs[r] += __shfl_xor(rs[r], off);
#pragma unroll
        for (int r = 0; r < 4; ++r)
            l4[r] = l4[r] * corr[r] + rs[r];
#pragma unroll
        for (int j = 0; j < 4; ++j)
#pragma unroll
            for (int r = 0; r < 4; ++r)
                o[j][r] *= corr[r];

        unsigned short* pw = Ps + wv * (16 * 72);
#pragma unroll
        for (int j = 0; j < 4; ++j)
#pragma unroll
            for (int r = 0; r < 4; ++r)
                pw[(lg * 4 + r) * 72 + j * 16 + lr] = f2bf_rne(sf[j][r]);

        __builtin_amdgcn_s_setprio(1);
#pragma unroll
        for (int kc = 0; kc < 2; ++kc) {
            bh8 pa = *(const bh8*)&pw[lr * 72 + kc * 32 + lg * 8];
            bh8 vb[4];
#pragma unroll
            for (int j = 0; j < 4; ++j)
                vb[j] = *(const bh8*)&Vs[(j * 16 + lr) * 72 + kc * 32 + lg * 8];
#pragma unroll
            for (int j = 0; j < 4; ++j)
                o[j] = __builtin_amdgcn_mfma_f32_16x16x32_bf16(pa, vb[j], o[j], 0, 0, 0);
        }
        __builtin_amdgcn_s_setprio(0);
    }

    float inv[4];
#pragma unroll
    for (int r = 0; r < 4; ++r) inv[r] = 1.f / l4[r];
    const int trow = b * SEQ + q0 + lg * 4;
#pragma unroll
    for (int r = 0; r < 4; ++r) {
        unsigned short* row = Ae2 + (size_t)(trow + r) * KE;
#pragma unroll
        for (int j = 0; j < 4; ++j) {
            const float v = o[j][r] * inv[r];
            const unsigned short hi = f2bf_rne(v);
            const unsigned short lo = f2bf_rne(v - bf2f(hi));
            const int c = h * HD + j * 16 + lr;
            row[c] = hi; row[768 + c] = hi; row[1536 + c] = lo;
        }
    }
}

// ---------------------------------------------------------------------------
extern "C" void kernel_launch(void* const* d_in, const int* in_sizes, int n_in,
                              void* d_out, int out_size, void* d_ws, size_t ws_size,
                              hipStream_t stream)
{
    const float* x      = (const float*)d_in[0];
    const float* W_qkv  = (const float*)d_in[1];
    const float* b_qkv  = (const float*)d_in[2];
    const float* W_gate = (const float*)d_in[3];
    const float* b_gate = (const float*)d_in[4];
    const float* A      = (const float*)d_in[5];
    const float* B_lora = (const float*)d_in[6];
    const float* W_proj = (const float*)d_in[7];
    const float* b_proj = (const float*)d_in[8];
    float* out = (float*)d_out;

    // workspace layout (shorts), ~80 MB total. Ae2 aliases A2 (disjoint lifetimes).
    unsigned short* A2  = (unsigned short*)d_ws;       // TT x KQ   (dead after QKV GEMM)
    unsigned short* B2  = A2 + (size_t)TT * KQ;        // D3 x KQ
    unsigned short* Qe  = B2 + (size_t)D3 * KQ;        // NBH x 512 x 192
    unsigned short* Ke  = Qe + (size_t)NBH * SEQ * EK; // NBH x 512 x 192
    unsigned short* Vt  = Ke + (size_t)NBH * SEQ * EK; // NBH x 64 x 512
    unsigned short* Wpe = Vt + (size_t)NBH * HD * SEQ; // D x KE
    unsigned short* Ae2 = A2;                          // TT x KE (written by attn)

    // 1. operand conversions + router/LoRA-down (router fills A2's 256-col tail)
    k_convert<KQ, true ><<<(TT * 192 + 255) / 256, 256, 0, stream>>>(x, A2, TT);
    k_convert<KQ, false><<<(D3 * 192 + 255) / 256, 256, 0, stream>>>(W_qkv, B2, D3);
    k_blora<<<(D3 * 128 + 255) / 256, 256, 0, stream>>>(B_lora, B2);
    k_router<<<TT, 64, 0, stream>>>(x, W_gate, b_gate, A, A2);
    k_convert<KE, false><<<(D * 192 + 255) / 256, 256, 0, stream>>>(W_proj, Wpe, D);

    // 2. QKV GEMM (bf16x3 + folded LoRA, K=2560) + fused Q/K/V-format epilogue
    //    128x96 tiles -> 24x32 = 768 blocks = exactly 3/CU
    {
        dim3 grid(D3 / 96, TT / 128);
        k_gemm_mfma<4, 3, 1><<<grid, 256, 0, stream>>>(
            A2, B2, b_qkv, nullptr, D3, KQ, Qe, Ke, Vt);
    }

    // 3. MFMA flash attention -> Ae2 (bf16x3, proj-ready)
    k_attn_mfma<<<NBH * 8, 256, 0, stream>>>(Qe, Ke, Vt, Ae2);

    // 4. output projection: 64x96 tiles -> 8x64 = 512 blocks = exactly 2/CU
    {
        dim3 grid(D / 96, TT / 64);
        k_gemm_mfma<2, 3, 0><<<grid, 256, 0, stream>>>(
            Ae2, Wpe, b_proj, out, D, KE, nullptr, nullptr, nullptr);
    }
}